// Round 1
// baseline (380.916 us; speedup 1.0000x reference)
//
#include <hip/hip_runtime.h>
#include <hip/hip_bf16.h>
#include <cstdint>
#include <cstddef>

typedef __bf16 bf16;
typedef __bf16 bf16x4_t __attribute__((ext_vector_type(4)));
typedef __bf16 bf16x8_t __attribute__((ext_vector_type(8)));
typedef float f32x4 __attribute__((ext_vector_type(4)));

#define DEV_INLINE __device__ __forceinline__

constexpr int BQ = 4, SEQ = 2048, DIM = 512, HEADS = 8, DH = 64;
constexpr int ROWS = BQ * SEQ;                    // 8192
constexpr float EPSF = 1.1920928955078125e-07f;   // np.finfo(float32).eps
constexpr float RSQRT_DIM = 0.04419417382415922f; // 512^-0.5

// ---------------- global->LDS direct (16B per lane) ----------------
DEV_INLINE void load_lds16(const void* g, void* l) {
  __builtin_amdgcn_global_load_lds(
      (const __attribute__((address_space(1))) void*)g,
      (__attribute__((address_space(3))) void*)l,
      16, 0, 0);
}

// ---------------- fp32 -> bf16 weight convert ----------------
__global__ __launch_bounds__(256) void cvt_bf16_k(const float* __restrict__ src,
                                                  bf16* __restrict__ dst, int n4) {
  int i = blockIdx.x * 256 + threadIdx.x;
  if (i >= n4) return;
  float4 f = reinterpret_cast<const float4*>(src)[i];
  bf16x4_t o;
  o[0] = (bf16)f.x; o[1] = (bf16)f.y; o[2] = (bf16)f.z; o[3] = (bf16)f.w;
  reinterpret_cast<bf16x4_t*>(dst)[i] = o;
}

// ---------------- RMSNorm (optionally fused positional encoding add) -------
// one block per row of 512; thread t handles cols 2t, 2t+1
template <bool ADDPOS>
__global__ __launch_bounds__(256) void rmsnorm_k(const float* __restrict__ in,
                                                 const float* __restrict__ gain,
                                                 const float* __restrict__ bias,
                                                 float* __restrict__ outF,
                                                 bf16* __restrict__ outB) {
  const int row = blockIdx.x;
  const int t = threadIdx.x;
  const float* rp = in + (size_t)row * DIM;
  float v0 = rp[2 * t], v1 = rp[2 * t + 1];
  if constexpr (ADDPOS) {
    const int s = row & (SEQ - 1);
    float e = (float)(2 * t) * (1.0f / (float)DIM);
    float dv = 1.0f / (powf(10000.0f, e) + EPSF);
    float ang = (float)s * dv;
    v0 += sinf(ang);
    v1 += cosf(ang);
  }
  float ss = v0 * v0 + v1 * v1;
#pragma unroll
  for (int off = 32; off > 0; off >>= 1) ss += __shfl_down(ss, off, 64);
  __shared__ float red[4];
  const int wave = t >> 6, lane = t & 63;
  if (lane == 0) red[wave] = ss;
  __syncthreads();
  float total = red[0] + red[1] + red[2] + red[3];
  float scale = sqrtf(total) * RSQRT_DIM;
  float inv = 1.0f / (scale + EPSF);
  if constexpr (ADDPOS) {
    float* op = outF + (size_t)row * DIM;
    op[2 * t] = v0;
    op[2 * t + 1] = v1;
  }
  bf16* hp = outB + (size_t)row * DIM;
  hp[2 * t]     = (bf16)(v0 * inv * gain[2 * t]     + bias[2 * t]);
  hp[2 * t + 1] = (bf16)(v1 * inv * gain[2 * t + 1] + bias[2 * t + 1]);
}

// ---------------- GEMM: C[M,N] = A[M,512] @ Bt[N,512]^T, bf16 in, f32 acc ---
// BM=128 BN=128 BK=32, 256 threads (4 waves 2x2), each wave 64x64 (4x4 frags)
enum { MODE_QKV = 0, MODE_RES = 1, MODE_BIAS = 2, MODE_SWIGLU = 3, MODE_RESBIAS = 4 };

template <int MODE>
__global__ __launch_bounds__(256) void gemm_bt_k(
    const bf16* __restrict__ A, const bf16* __restrict__ Bt,
    const float* __restrict__ bias, const float* __restrict__ res,
    float* __restrict__ outF, bf16* __restrict__ outB,
    bf16* __restrict__ oq, bf16* __restrict__ okk, bf16* __restrict__ ovT) {
  __shared__ __align__(16) bf16 sA[128 * 32];
  __shared__ __align__(16) bf16 sB[128 * 32];
  const int tid = threadIdx.x;
  const int wave = tid >> 6, lane = tid & 63;
  const int m0 = blockIdx.x * 128, n0 = blockIdx.y * 128;
  const int wm = wave >> 1, wn = wave & 1;
  const int lr = lane & 15, lk = (lane >> 4) * 8;

  const f32x4 fzero = {0.f, 0.f, 0.f, 0.f};
  f32x4 acc[4][4];
#pragma unroll
  for (int i = 0; i < 4; ++i)
#pragma unroll
    for (int j = 0; j < 4; ++j) acc[i][j] = fzero;

  const int off0 = wave * 1024 + lane * 16;  // byte offset within 4KB part

  for (int kt = 0; kt < 16; ++kt) {
    const int k0 = kt * 32;
    __syncthreads();
#pragma unroll
    for (int part = 0; part < 2; ++part) {
      const int off = part * 4096 + off0;
      const int row = off >> 6, colb = off & 63;
      load_lds16((const char*)A + ((size_t)(m0 + row) * 512 + k0) * 2 + colb,
                 (char*)sA + part * 4096 + wave * 1024);
      load_lds16((const char*)Bt + ((size_t)(n0 + row) * 512 + k0) * 2 + colb,
                 (char*)sB + part * 4096 + wave * 1024);
    }
    __syncthreads();
    bf16x8_t af[4], bfr[4];
#pragma unroll
    for (int mf = 0; mf < 4; ++mf)
      af[mf] = *(const bf16x8_t*)(sA + (wm * 64 + mf * 16 + lr) * 32 + lk);
#pragma unroll
    for (int nf = 0; nf < 4; ++nf)
      bfr[nf] = *(const bf16x8_t*)(sB + (wn * 64 + nf * 16 + lr) * 32 + lk);
#pragma unroll
    for (int mf = 0; mf < 4; ++mf)
#pragma unroll
      for (int nf = 0; nf < 4; ++nf)
        acc[mf][nf] = __builtin_amdgcn_mfma_f32_16x16x32_bf16(af[mf], bfr[nf],
                                                              acc[mf][nf], 0, 0, 0);
  }

  // epilogue: C row = (lane>>4)*4+reg (+16*mf), col = lane&15 (+16*nf)
  const int rbase = m0 + wm * 64 + (lane >> 4) * 4;
  const int cbase = n0 + wn * 64 + lr;
#pragma unroll
  for (int mf = 0; mf < 4; ++mf) {
#pragma unroll
    for (int nf = 0; nf < 4; ++nf) {
      const int c = cbase + nf * 16;
#pragma unroll
      for (int rg = 0; rg < 4; ++rg) {
        const int r = rbase + mf * 16 + rg;
        float v = acc[mf][nf][rg];
        if constexpr (MODE == MODE_QKV) {
          const int which = c >> 9, cc = c & 511;
          const int b = r >> 11, s = r & 2047;
          const int h = cc >> 6, dh = cc & 63;
          const size_t bh = (size_t)(b * HEADS + h);
          if (which == 0)      oq [(bh * SEQ + s) * DH + dh] = (bf16)v;
          else if (which == 1) okk[(bh * SEQ + s) * DH + dh] = (bf16)v;
          else                 ovT[(bh * DH + dh) * SEQ + s] = (bf16)v;  // V^T
        } else if constexpr (MODE == MODE_RES) {
          const size_t idx = (size_t)r * 512 + c;
          outF[idx] = res[idx] + v;
        } else if constexpr (MODE == MODE_BIAS) {
          const size_t idx = (size_t)r * 512 + c;
          outF[idx] = v + bias[c];
        } else if constexpr (MODE == MODE_SWIGLU) {
          const size_t idx = (size_t)r * 512 + c;
          float u1 = res[idx];
          float sig = 1.0f / (1.0f + __expf(-u1));
          outB[idx] = (bf16)(u1 * sig + v + bias[c]);
        } else {  // MODE_RESBIAS
          const size_t idx = (size_t)r * 512 + c;
          outF[idx] = res[idx] + v + bias[c];
        }
      }
    }
  }
}

// ---------------- causal flash attention ----------------
// grid (32 qtiles, 32 bh), 256 threads; wave w owns q rows qb..qb+15.
// scores tile 16q x 64k via 8 MFMA; online softmax; PV via V^T (B^T form).
__global__ __launch_bounds__(256) void attn_k(const bf16* __restrict__ Q,
                                              const bf16* __restrict__ K,
                                              const bf16* __restrict__ VT,
                                              bf16* __restrict__ O) {
  const int tid = threadIdx.x, wave = tid >> 6, lane = tid & 63;
  const int bh = blockIdx.y;
  const int qb = blockIdx.x * 64 + wave * 16;
  const bf16* Qb = Q + (size_t)bh * SEQ * DH;
  const bf16* Kb = K + (size_t)bh * SEQ * DH;
  const bf16* Vb = VT + (size_t)bh * DH * SEQ;  // [dh][s]
  const int lr = lane & 15, lk = (lane >> 4) * 8;

  bf16x8_t qf[2];
  qf[0] = *(const bf16x8_t*)(Qb + (size_t)(qb + lr) * DH + lk);
  qf[1] = *(const bf16x8_t*)(Qb + (size_t)(qb + lr) * DH + 32 + lk);

  const f32x4 fzero = {0.f, 0.f, 0.f, 0.f};
  f32x4 oacc[4];
  float mrun[4], lrun[4];
#pragma unroll
  for (int i = 0; i < 4; ++i) { oacc[i] = fzero; mrun[i] = -3.0e38f; lrun[i] = 0.f; }

  __shared__ __align__(16) bf16 pls[4][16][80];  // per-wave P tile (padded)

  const int ktend = qb >> 6;  // tile containing the diagonal
  for (int kt = 0; kt <= ktend; ++kt) {
    f32x4 sc[4];
#pragma unroll
    for (int i = 0; i < 4; ++i) sc[i] = fzero;
#pragma unroll
    for (int nf = 0; nf < 4; ++nf) {
      const bf16* kp = Kb + (size_t)(kt * 64 + nf * 16 + lr) * DH + lk;
      bf16x8_t b0 = *(const bf16x8_t*)(kp);
      bf16x8_t b1 = *(const bf16x8_t*)(kp + 32);
      sc[nf] = __builtin_amdgcn_mfma_f32_16x16x32_bf16(qf[0], b0, sc[nf], 0, 0, 0);
      sc[nf] = __builtin_amdgcn_mfma_f32_16x16x32_bf16(qf[1], b1, sc[nf], 0, 0, 0);
    }
    const bool last = (kt == ktend);
    float p[4][4];  // [nf][reg]
    float mt[4];
#pragma unroll
    for (int r = 0; r < 4; ++r) mt[r] = -3.0e38f;
#pragma unroll
    for (int nf = 0; nf < 4; ++nf) {
#pragma unroll
      for (int r = 0; r < 4; ++r) {
        float sv = sc[nf][r] * RSQRT_DIM;
        if (last) {
          int kg = kt * 64 + nf * 16 + lr;
          int qg = qb + (lane >> 4) * 4 + r;
          if (kg > qg) sv = -3.0e38f;
        }
        p[nf][r] = sv;
        mt[r] = fmaxf(mt[r], sv);
      }
    }
#pragma unroll
    for (int r = 0; r < 4; ++r) {
      float v = mt[r];
      v = fmaxf(v, __shfl_xor(v, 1));
      v = fmaxf(v, __shfl_xor(v, 2));
      v = fmaxf(v, __shfl_xor(v, 4));
      v = fmaxf(v, __shfl_xor(v, 8));
      mt[r] = v;
    }
    float alpha[4];
#pragma unroll
    for (int r = 0; r < 4; ++r) {
      float mnew = fmaxf(mrun[r], mt[r]);
      alpha[r] = __expf(mrun[r] - mnew);
      mrun[r] = mnew;
      float s = 0.f;
#pragma unroll
      for (int nf = 0; nf < 4; ++nf) {
        float e = __expf(p[nf][r] - mnew);
        p[nf][r] = e;
        s += e;
      }
      // row-sum across the 16 lanes
      s += __shfl_xor(s, 1);
      s += __shfl_xor(s, 2);
      s += __shfl_xor(s, 4);
      s += __shfl_xor(s, 8);
      lrun[r] = lrun[r] * alpha[r] + s;
    }
#pragma unroll
    for (int nf = 0; nf < 4; ++nf)
#pragma unroll
      for (int r = 0; r < 4; ++r) oacc[nf][r] *= alpha[r];
    // P -> LDS (C layout -> A layout transpose through LDS)
#pragma unroll
    for (int nf = 0; nf < 4; ++nf)
#pragma unroll
      for (int r = 0; r < 4; ++r)
        pls[wave][(lane >> 4) * 4 + r][nf * 16 + lr] = (bf16)p[nf][r];
    bf16x8_t pa0 = *(const bf16x8_t*)&pls[wave][lr][lk];
    bf16x8_t pa1 = *(const bf16x8_t*)&pls[wave][lr][32 + lk];
#pragma unroll
    for (int nf = 0; nf < 4; ++nf) {
      const bf16* vp = Vb + (size_t)(nf * 16 + lr) * SEQ + kt * 64 + lk;
      bf16x8_t v0 = *(const bf16x8_t*)(vp);
      bf16x8_t v1 = *(const bf16x8_t*)(vp + 32);
      oacc[nf] = __builtin_amdgcn_mfma_f32_16x16x32_bf16(pa0, v0, oacc[nf], 0, 0, 0);
      oacc[nf] = __builtin_amdgcn_mfma_f32_16x16x32_bf16(pa1, v1, oacc[nf], 0, 0, 0);
    }
  }
  // write O as [B,S,H*DH] bf16
  const int b = bh >> 3, h = bh & 7;
#pragma unroll
  for (int nf = 0; nf < 4; ++nf) {
#pragma unroll
    for (int r = 0; r < 4; ++r) {
      const int qg = qb + (lane >> 4) * 4 + r;
      float v = oacc[nf][r] / lrun[r];
      O[((size_t)(b * SEQ + qg)) * DIM + h * DH + nf * 16 + lr] = (bf16)v;
    }
  }
}

// ---------------- host launcher ----------------
extern "C" void kernel_launch(void* const* d_in, const int* in_sizes, int n_in,
                              void* d_out, int out_size, void* d_ws, size_t ws_size,
                              hipStream_t stream) {
  const float* x   = (const float*)d_in[0];
  const float* n1g = (const float*)d_in[1];
  const float* n1b = (const float*)d_in[2];
  const float* wq  = (const float*)d_in[3];
  const float* wk  = (const float*)d_in[4];
  const float* wv  = (const float*)d_in[5];
  const float* wo  = (const float*)d_in[6];
  const float* n2g = (const float*)d_in[7];
  const float* n2b = (const float*)d_in[8];
  const float* w1  = (const float*)d_in[9];
  const float* b1  = (const float*)d_in[10];
  const float* ffg = (const float*)d_in[11];
  const float* ffb = (const float*)d_in[12];
  const float* sww = (const float*)d_in[13];
  const float* swb = (const float*)d_in[14];
  const float* w2  = (const float*)d_in[15];
  const float* b2  = (const float*)d_in[16];
  float* out = (float*)d_out;

  char* ws = (char*)d_ws;
  // f32 buffers
  float* x1 = (float*)(ws + 0);            // 16 MiB (also reused for t and u1)
  float* x2 = (float*)(ws + 16777216);     // 16 MiB
  // bf16 buffers
  bf16* hbuf   = (bf16*)(ws + 33554432);   // 8 MiB (h1/h2/h3)
  bf16* qbuf   = (bf16*)(ws + 41943040);   // 8 MiB (q, later g)
  bf16* kbuf   = (bf16*)(ws + 50331648);   // 8 MiB
  bf16* vtbuf  = (bf16*)(ws + 58720256);   // 8 MiB (V^T)
  bf16* obuf   = (bf16*)(ws + 67108864);   // 8 MiB
  bf16* wqkv_b = (bf16*)(ws + 75497472);   // 1.5 MiB
  bf16* wo_b   = (bf16*)(ws + 77070336);
  bf16* w1_b   = (bf16*)(ws + 77594624);
  bf16* sw_b16 = (bf16*)(ws + 78118912);   // 1 MiB [1024][512]
  bf16* w2_b   = (bf16*)(ws + 79167488);

  // weight conversion fp32 -> bf16 (packed QKV)
  cvt_bf16_k<<<256, 256, 0, stream>>>(wq, wqkv_b,          65536);
  cvt_bf16_k<<<256, 256, 0, stream>>>(wk, wqkv_b + 262144, 65536);
  cvt_bf16_k<<<256, 256, 0, stream>>>(wv, wqkv_b + 524288, 65536);
  cvt_bf16_k<<<256, 256, 0, stream>>>(wo, wo_b, 65536);
  cvt_bf16_k<<<256, 256, 0, stream>>>(w1, w1_b, 65536);
  cvt_bf16_k<<<512, 256, 0, stream>>>(sww, sw_b16, 131072);
  cvt_bf16_k<<<256, 256, 0, stream>>>(w2, w2_b, 65536);

  // x1 = x + pos ; h1 = rmsnorm(x1)
  rmsnorm_k<true><<<ROWS, 256, 0, stream>>>(x, n1g, n1b, x1, hbuf);

  // q,k,vT = h1 @ wqkv^T  (N=1536)
  gemm_bt_k<MODE_QKV><<<dim3(64, 12), 256, 0, stream>>>(
      hbuf, wqkv_b, nullptr, nullptr, nullptr, nullptr, qbuf, kbuf, vtbuf);

  // causal attention -> obuf [B,S,D]
  attn_k<<<dim3(32, 32), 256, 0, stream>>>(qbuf, kbuf, vtbuf, obuf);

  // x2 = x1 + obuf @ wo^T
  gemm_bt_k<MODE_RES><<<dim3(64, 4), 256, 0, stream>>>(
      obuf, wo_b, nullptr, x1, x2, nullptr, nullptr, nullptr, nullptr);

  // h2 = rmsnorm(x2)
  rmsnorm_k<false><<<ROWS, 256, 0, stream>>>(x2, n2g, n2b, nullptr, hbuf);

  // t = h2 @ ff_w1^T + b1   (into x1 space)
  gemm_bt_k<MODE_BIAS><<<dim3(64, 4), 256, 0, stream>>>(
      hbuf, w1_b, b1, nullptr, x1, nullptr, nullptr, nullptr, nullptr);

  // h3 = rmsnorm(t)
  rmsnorm_k<false><<<ROWS, 256, 0, stream>>>(x1, ffg, ffb, nullptr, hbuf);

  // u1 = h3 @ sw_w[:512]^T + sw_b[:512]  (into x1 space)
  gemm_bt_k<MODE_BIAS><<<dim3(64, 4), 256, 0, stream>>>(
      hbuf, sw_b16, swb, nullptr, x1, nullptr, nullptr, nullptr, nullptr);

  // g = silu(u1) + h3 @ sw_w[512:]^T + sw_b[512:]  -> bf16 into qbuf
  gemm_bt_k<MODE_SWIGLU><<<dim3(64, 4), 256, 0, stream>>>(
      hbuf, sw_b16 + 512 * 512, swb + 512, x1, nullptr, qbuf,
      nullptr, nullptr, nullptr);

  // out = x2 + g @ ff_w2^T + b2
  gemm_bt_k<MODE_RESBIAS><<<dim3(64, 4), 256, 0, stream>>>(
      qbuf, w2_b, b2, x2, out, nullptr, nullptr, nullptr, nullptr);
}

// Round 2
// 258.641 us; speedup vs baseline: 1.4728x; 1.4728x over previous
//
#include <hip/hip_runtime.h>
#include <hip/hip_bf16.h>
#include <cstdint>
#include <cstddef>

typedef __bf16 bf16;
typedef __bf16 bf16x4_t __attribute__((ext_vector_type(4)));
typedef __bf16 bf16x8_t __attribute__((ext_vector_type(8)));
typedef float f32x4 __attribute__((ext_vector_type(4)));
typedef float f32x16 __attribute__((ext_vector_type(16)));

#define DEV_INLINE __device__ __forceinline__

constexpr int BQ = 4, SEQ = 2048, DIM = 512, HEADS = 8, DH = 64;
constexpr int ROWS = BQ * SEQ;                    // 8192
constexpr float EPSF = 1.1920928955078125e-07f;   // np.finfo(float32).eps
constexpr float RSQRT_DIM = 0.04419417382415922f; // 512^-0.5

// ---------------- global->LDS direct (16B per lane) ----------------
DEV_INLINE void load_lds16(const void* g, void* l) {
  __builtin_amdgcn_global_load_lds(
      (const __attribute__((address_space(1))) void*)g,
      (__attribute__((address_space(3))) void*)l,
      16, 0, 0);
}

DEV_INLINE unsigned int packbf(float a, float b) {
  union { unsigned int u; bf16 h[2]; } z;
  z.h[0] = (bf16)a;
  z.h[1] = (bf16)b;
  return z.u;
}

// ---------------- fp32 -> bf16 weight convert ----------------
__global__ __launch_bounds__(256) void cvt_bf16_k(const float* __restrict__ src,
                                                  bf16* __restrict__ dst, int n4) {
  int i = blockIdx.x * 256 + threadIdx.x;
  if (i >= n4) return;
  float4 f = reinterpret_cast<const float4*>(src)[i];
  bf16x4_t o;
  o[0] = (bf16)f.x; o[1] = (bf16)f.y; o[2] = (bf16)f.z; o[3] = (bf16)f.w;
  reinterpret_cast<bf16x4_t*>(dst)[i] = o;
}

// ---------------- RMSNorm (optionally fused positional encoding add) -------
template <bool ADDPOS>
__global__ __launch_bounds__(256) void rmsnorm_k(const float* __restrict__ in,
                                                 const float* __restrict__ gain,
                                                 const float* __restrict__ bias,
                                                 float* __restrict__ outF,
                                                 bf16* __restrict__ outB) {
  const int row = blockIdx.x;
  const int t = threadIdx.x;
  const float* rp = in + (size_t)row * DIM;
  float v0 = rp[2 * t], v1 = rp[2 * t + 1];
  if constexpr (ADDPOS) {
    const int s = row & (SEQ - 1);
    float e = (float)(2 * t) * (1.0f / (float)DIM);
    float dv = 1.0f / (powf(10000.0f, e) + EPSF);
    float ang = (float)s * dv;
    v0 += sinf(ang);
    v1 += cosf(ang);
  }
  float ss = v0 * v0 + v1 * v1;
#pragma unroll
  for (int off = 32; off > 0; off >>= 1) ss += __shfl_down(ss, off, 64);
  __shared__ float red[4];
  const int wave = t >> 6, lane = t & 63;
  if (lane == 0) red[wave] = ss;
  __syncthreads();
  float total = red[0] + red[1] + red[2] + red[3];
  float scale = sqrtf(total) * RSQRT_DIM;
  float inv = 1.0f / (scale + EPSF);
  if constexpr (ADDPOS) {
    float* op = outF + (size_t)row * DIM;
    op[2 * t] = v0;
    op[2 * t + 1] = v1;
  }
  bf16* hp = outB + (size_t)row * DIM;
  hp[2 * t]     = (bf16)(v0 * inv * gain[2 * t]     + bias[2 * t]);
  hp[2 * t + 1] = (bf16)(v1 * inv * gain[2 * t + 1] + bias[2 * t + 1]);
}

// ---------------- GEMM: C[M,N] = A[M,512] @ Bt[N,512]^T, bf16 in, f32 acc ---
enum { MODE_QKV = 0, MODE_RES = 1, MODE_BIAS = 2, MODE_SWIGLU = 3, MODE_RESBIAS = 4 };

template <int MODE>
__global__ __launch_bounds__(256) void gemm_bt_k(
    const bf16* __restrict__ A, const bf16* __restrict__ Bt,
    const float* __restrict__ bias, const float* __restrict__ res,
    float* __restrict__ outF, bf16* __restrict__ outB,
    bf16* __restrict__ oq, bf16* __restrict__ okk, bf16* __restrict__ ovT) {
  __shared__ __align__(16) bf16 sA[128 * 32];
  __shared__ __align__(16) bf16 sB[128 * 32];
  const int tid = threadIdx.x;
  const int wave = tid >> 6, lane = tid & 63;
  const int m0 = blockIdx.x * 128, n0 = blockIdx.y * 128;
  const int wm = wave >> 1, wn = wave & 1;
  const int lr = lane & 15, lk = (lane >> 4) * 8;

  const f32x4 fzero = {0.f, 0.f, 0.f, 0.f};
  f32x4 acc[4][4];
#pragma unroll
  for (int i = 0; i < 4; ++i)
#pragma unroll
    for (int j = 0; j < 4; ++j) acc[i][j] = fzero;

  const int off0 = wave * 1024 + lane * 16;

  for (int kt = 0; kt < 16; ++kt) {
    const int k0 = kt * 32;
    __syncthreads();
#pragma unroll
    for (int part = 0; part < 2; ++part) {
      const int off = part * 4096 + off0;
      const int row = off >> 6, colb = off & 63;
      load_lds16((const char*)A + ((size_t)(m0 + row) * 512 + k0) * 2 + colb,
                 (char*)sA + part * 4096 + wave * 1024);
      load_lds16((const char*)Bt + ((size_t)(n0 + row) * 512 + k0) * 2 + colb,
                 (char*)sB + part * 4096 + wave * 1024);
    }
    __syncthreads();
    bf16x8_t af[4], bfr[4];
#pragma unroll
    for (int mf = 0; mf < 4; ++mf)
      af[mf] = *(const bf16x8_t*)(sA + (wm * 64 + mf * 16 + lr) * 32 + lk);
#pragma unroll
    for (int nf = 0; nf < 4; ++nf)
      bfr[nf] = *(const bf16x8_t*)(sB + (wn * 64 + nf * 16 + lr) * 32 + lk);
#pragma unroll
    for (int mf = 0; mf < 4; ++mf)
#pragma unroll
      for (int nf = 0; nf < 4; ++nf)
        acc[mf][nf] = __builtin_amdgcn_mfma_f32_16x16x32_bf16(af[mf], bfr[nf],
                                                              acc[mf][nf], 0, 0, 0);
  }

  const int rbase = m0 + wm * 64 + (lane >> 4) * 4;
  const int cbase = n0 + wn * 64 + lr;
#pragma unroll
  for (int mf = 0; mf < 4; ++mf) {
#pragma unroll
    for (int nf = 0; nf < 4; ++nf) {
      const int c = cbase + nf * 16;
#pragma unroll
      for (int rg = 0; rg < 4; ++rg) {
        const int r = rbase + mf * 16 + rg;
        float v = acc[mf][nf][rg];
        if constexpr (MODE == MODE_QKV) {
          const int which = c >> 9, cc = c & 511;
          const int b = r >> 11, s = r & 2047;
          const int h = cc >> 6, dh = cc & 63;
          const size_t bh = (size_t)(b * HEADS + h);
          if (which == 0)      oq [(bh * SEQ + s) * DH + dh] = (bf16)(v * RSQRT_DIM);
          else if (which == 1) okk[(bh * SEQ + s) * DH + dh] = (bf16)v;
          else                 ovT[(bh * DH + dh) * SEQ + s] = (bf16)v;  // V^T
        } else if constexpr (MODE == MODE_RES) {
          const size_t idx = (size_t)r * 512 + c;
          outF[idx] = res[idx] + v;
        } else if constexpr (MODE == MODE_BIAS) {
          const size_t idx = (size_t)r * 512 + c;
          outF[idx] = v + bias[c];
        } else if constexpr (MODE == MODE_SWIGLU) {
          const size_t idx = (size_t)r * 512 + c;
          float u1 = res[idx];
          float sig = 1.0f / (1.0f + __expf(-u1));
          outB[idx] = (bf16)(u1 * sig + v + bias[c]);
        } else {
          const size_t idx = (size_t)r * 512 + c;
          outF[idx] = res[idx] + v + bias[c];
        }
      }
    }
  }
}

// ---------------- causal flash attention, swapped-QK^T 32x32 ----------------
// 256 blocks x 512 threads. Block -> (bh, pair i). Waves 0-3: q-tile i,
// waves 4-7: q-tile 15-i (128 rows each, 32 rows/wave). Per k-iter (KVBLK=64):
// scores^T = K.Q^T via 8 mfma_32x32x16 -> lane holds 32 scores of ONE q-row
// (q = lane&31, k = crow(r,hi)) -> in-register softmax (1 shfl_xor(32)) ->
// pack P to bf16 B-frags (8 shfl_xor) -> O^T += V^T.P via 8 mfma.
// q pre-scaled by DIM^-0.5 in the QKV epilogue. No barriers.
__global__ __launch_bounds__(512) void attn_k(const bf16* __restrict__ Q,
                                              const bf16* __restrict__ K,
                                              const bf16* __restrict__ VT,
                                              bf16* __restrict__ O) {
  const int tid = threadIdx.x;
  const int wave = tid >> 6, lane = tid & 63;
  const int lq = lane & 31, hi = lane >> 5;

  const int wg = blockIdx.x;          // 0..255
  const int xcd = wg & 7, slot = wg >> 3;
  const int bh = xcd * 4 + (slot >> 3);
  const int ip = slot & 7;
  const int tile = (wave < 4) ? ip : (15 - ip);
  const int qw = tile * 128 + (wave & 3) * 32;

  const bf16* Qb = Q + (size_t)bh * SEQ * DH;
  const bf16* Kb = K + (size_t)bh * SEQ * DH;
  const bf16* Vb = VT + (size_t)bh * DH * SEQ;

  __shared__ __align__(16) bf16 olds[8][32][80];

  // Q fragments: B-operand of K.Q^T — lane: q-col = lq, dh = 16s + 8hi + j
  bf16x8_t qf[4];
  {
    const bf16* qp = Qb + (size_t)(qw + lq) * DH + 8 * hi;
    qf[0] = *(const bf16x8_t*)(qp);
    qf[1] = *(const bf16x8_t*)(qp + 16);
    qf[2] = *(const bf16x8_t*)(qp + 32);
    qf[3] = *(const bf16x8_t*)(qp + 48);
  }

  f32x16 oa0, oa1;
#pragma unroll
  for (int r = 0; r < 16; ++r) { oa0[r] = 0.f; oa1[r] = 0.f; }
  float mrun = -3.0e38f, lrun = 0.f;

  const int nkt = (qw >> 6) + 1;
  for (int kt = 0; kt < nkt; ++kt) {
    // ---- scores^T: two 32x32 tiles (k blocks b=0,1) ----
    f32x16 s0, s1;
#pragma unroll
    for (int r = 0; r < 16; ++r) { s0[r] = 0.f; s1[r] = 0.f; }
    const bf16* kp0 = Kb + (size_t)(kt * 64 + lq) * DH + 8 * hi;
    const bf16* kp1 = kp0 + 32 * DH;
#pragma unroll
    for (int s = 0; s < 4; ++s) {
      s0 = __builtin_amdgcn_mfma_f32_32x32x16_bf16(*(const bf16x8_t*)(kp0 + 16 * s),
                                                   qf[s], s0, 0, 0, 0);
      s1 = __builtin_amdgcn_mfma_f32_32x32x16_bf16(*(const bf16x8_t*)(kp1 + 16 * s),
                                                   qf[s], s1, 0, 0, 0);
    }

    // ---- mask (last tile) + row max ----
    const bool last = (kt == nkt - 1);
    const int qg = qw + lq;
    float mt = -3.0e38f;
#pragma unroll
    for (int r = 0; r < 16; ++r) {
      float a = s0[r], b = s1[r];
      if (last) {
        const int kl = kt * 64 + (r & 3) + 8 * (r >> 2) + 4 * hi;
        if (kl > qg) a = -3.0e38f;
        if (kl + 32 > qg) b = -3.0e38f;
        s0[r] = a; s1[r] = b;
      }
      mt = fmaxf(mt, fmaxf(a, b));
    }
    mt = fmaxf(mt, __shfl_xor(mt, 32));
    const float mnew = fmaxf(mrun, mt);
    const float alpha = __expf(mrun - mnew);
    mrun = mnew;

    // ---- exp + row sum ----
    float sum = 0.f;
#pragma unroll
    for (int r = 0; r < 16; ++r) {
      float a = __expf(s0[r] - mnew); s0[r] = a; sum += a;
      float b = __expf(s1[r] - mnew); s1[r] = b; sum += b;
    }
    sum += __shfl_xor(sum, 32);
    lrun = lrun * alpha + sum;

    // ---- rescale O^T ----
#pragma unroll
    for (int r = 0; r < 16; ++r) { oa0[r] *= alpha; oa1[r] *= alpha; }

    // ---- pack P (f32, k=crow) -> PV B-fragments (kk = 8hi+j) ----
    unsigned int wa0[4], wb0[4], wa1[4], wb1[4];
#pragma unroll
    for (int t = 0; t < 4; ++t) {
      wa0[t] = packbf(s0[4 * t], s0[4 * t + 1]);
      wb0[t] = packbf(s0[4 * t + 2], s0[4 * t + 3]);
      wa1[t] = packbf(s1[4 * t], s1[4 * t + 1]);
      wb1[t] = packbf(s1[4 * t + 2], s1[4 * t + 3]);
    }
    unsigned int xa0[4], xb0[4], xa1[4], xb1[4];
#pragma unroll
    for (int t = 0; t < 4; ++t) {
      xa0[t] = __shfl_xor((int)wa0[t], 32);
      xb0[t] = __shfl_xor((int)wb0[t], 32);
      xa1[t] = __shfl_xor((int)wa1[t], 32);
      xb1[t] = __shfl_xor((int)wb1[t], 32);
    }
    union U8 { unsigned int u[4]; bf16x8_t v; };
    U8 p00, p01, p10, p11;  // p<block><sub16>
    p00.u[0] = hi ? xa0[1] : wa0[0]; p00.u[1] = hi ? xb0[1] : wb0[0];
    p00.u[2] = hi ? wa0[1] : xa0[0]; p00.u[3] = hi ? wb0[1] : xb0[0];
    p01.u[0] = hi ? xa0[3] : wa0[2]; p01.u[1] = hi ? xb0[3] : wb0[2];
    p01.u[2] = hi ? wa0[3] : xa0[2]; p01.u[3] = hi ? wb0[3] : xb0[2];
    p10.u[0] = hi ? xa1[1] : wa1[0]; p10.u[1] = hi ? xb1[1] : wb1[0];
    p10.u[2] = hi ? wa1[1] : xa1[0]; p10.u[3] = hi ? wb1[1] : xb1[0];
    p11.u[0] = hi ? xa1[3] : wa1[2]; p11.u[1] = hi ? xb1[3] : wb1[2];
    p11.u[2] = hi ? wa1[3] : xa1[2]; p11.u[3] = hi ? wb1[3] : xb1[2];

    // ---- O^T += V^T . P  (A = V^T rows d, B = P) ----
    const bf16* vp0 = Vb + (size_t)lq * SEQ + kt * 64 + 8 * hi;
    const bf16* vp1 = Vb + (size_t)(32 + lq) * SEQ + kt * 64 + 8 * hi;
    oa0 = __builtin_amdgcn_mfma_f32_32x32x16_bf16(*(const bf16x8_t*)(vp0 +  0), p00.v, oa0, 0, 0, 0);
    oa0 = __builtin_amdgcn_mfma_f32_32x32x16_bf16(*(const bf16x8_t*)(vp0 + 16), p01.v, oa0, 0, 0, 0);
    oa0 = __builtin_amdgcn_mfma_f32_32x32x16_bf16(*(const bf16x8_t*)(vp0 + 32), p10.v, oa0, 0, 0, 0);
    oa0 = __builtin_amdgcn_mfma_f32_32x32x16_bf16(*(const bf16x8_t*)(vp0 + 48), p11.v, oa0, 0, 0, 0);
    oa1 = __builtin_amdgcn_mfma_f32_32x32x16_bf16(*(const bf16x8_t*)(vp1 +  0), p00.v, oa1, 0, 0, 0);
    oa1 = __builtin_amdgcn_mfma_f32_32x32x16_bf16(*(const bf16x8_t*)(vp1 + 16), p01.v, oa1, 0, 0, 0);
    oa1 = __builtin_amdgcn_mfma_f32_32x32x16_bf16(*(const bf16x8_t*)(vp1 + 32), p10.v, oa1, 0, 0, 0);
    oa1 = __builtin_amdgcn_mfma_f32_32x32x16_bf16(*(const bf16x8_t*)(vp1 + 48), p11.v, oa1, 0, 0, 0);
  }

  // ---- epilogue: /l, transpose through LDS, coalesced store ----
  const float inv = 1.0f / lrun;
  bf16* ol = &olds[wave][0][0];  // [32][80]
#pragma unroll
  for (int t = 0; t < 4; ++t) {
    const int d0 = 8 * t + 4 * hi;  // rows d of O^T held in regs 4t..4t+3
    *(unsigned int*)(ol + lq * 80 + d0) =
        packbf(oa0[4 * t] * inv, oa0[4 * t + 1] * inv);
    *(unsigned int*)(ol + lq * 80 + d0 + 2) =
        packbf(oa0[4 * t + 2] * inv, oa0[4 * t + 3] * inv);
    *(unsigned int*)(ol + lq * 80 + 32 + d0) =
        packbf(oa1[4 * t] * inv, oa1[4 * t + 1] * inv);
    *(unsigned int*)(ol + lq * 80 + 32 + d0 + 2) =
        packbf(oa1[4 * t + 2] * inv, oa1[4 * t + 3] * inv);
  }
  const int b = bh >> 3, h = bh & 7;
#pragma unroll
  for (int ps = 0; ps < 4; ++ps) {
    const int flat = ps * 1024 + lane * 16;  // bytes within 32 rows x 128B
    const int qr = flat >> 7, off = flat & 127;
    bf16x8_t vv = *(const bf16x8_t*)((const char*)ol + qr * 160 + off);
    *(bf16x8_t*)(O + ((size_t)(b * SEQ + qw + qr)) * DIM + h * 64 + off / 2) = vv;
  }
}

// ---------------- host launcher ----------------
extern "C" void kernel_launch(void* const* d_in, const int* in_sizes, int n_in,
                              void* d_out, int out_size, void* d_ws, size_t ws_size,
                              hipStream_t stream) {
  const float* x   = (const float*)d_in[0];
  const float* n1g = (const float*)d_in[1];
  const float* n1b = (const float*)d_in[2];
  const float* wq  = (const float*)d_in[3];
  const float* wk  = (const float*)d_in[4];
  const float* wv  = (const float*)d_in[5];
  const float* wo  = (const float*)d_in[6];
  const float* n2g = (const float*)d_in[7];
  const float* n2b = (const float*)d_in[8];
  const float* w1  = (const float*)d_in[9];
  const float* b1  = (const float*)d_in[10];
  const float* ffg = (const float*)d_in[11];
  const float* ffb = (const float*)d_in[12];
  const float* sww = (const float*)d_in[13];
  const float* swb = (const float*)d_in[14];
  const float* w2  = (const float*)d_in[15];
  const float* b2  = (const float*)d_in[16];
  float* out = (float*)d_out;

  char* ws = (char*)d_ws;
  float* x1 = (float*)(ws + 0);            // 16 MiB
  float* x2 = (float*)(ws + 16777216);     // 16 MiB
  bf16* hbuf   = (bf16*)(ws + 33554432);   // 8 MiB
  bf16* qbuf   = (bf16*)(ws + 41943040);   // 8 MiB
  bf16* kbuf   = (bf16*)(ws + 50331648);   // 8 MiB
  bf16* vtbuf  = (bf16*)(ws + 58720256);   // 8 MiB (V^T)
  bf16* obuf   = (bf16*)(ws + 67108864);   // 8 MiB
  bf16* wqkv_b = (bf16*)(ws + 75497472);   // 1.5 MiB
  bf16* wo_b   = (bf16*)(ws + 77070336);
  bf16* w1_b   = (bf16*)(ws + 77594624);
  bf16* sw_b16 = (bf16*)(ws + 78118912);   // 1 MiB
  bf16* w2_b   = (bf16*)(ws + 79167488);

  cvt_bf16_k<<<256, 256, 0, stream>>>(wq, wqkv_b,          65536);
  cvt_bf16_k<<<256, 256, 0, stream>>>(wk, wqkv_b + 262144, 65536);
  cvt_bf16_k<<<256, 256, 0, stream>>>(wv, wqkv_b + 524288, 65536);
  cvt_bf16_k<<<256, 256, 0, stream>>>(wo, wo_b, 65536);
  cvt_bf16_k<<<256, 256, 0, stream>>>(w1, w1_b, 65536);
  cvt_bf16_k<<<512, 256, 0, stream>>>(sww, sw_b16, 131072);
  cvt_bf16_k<<<256, 256, 0, stream>>>(w2, w2_b, 65536);

  rmsnorm_k<true><<<ROWS, 256, 0, stream>>>(x, n1g, n1b, x1, hbuf);

  gemm_bt_k<MODE_QKV><<<dim3(64, 12), 256, 0, stream>>>(
      hbuf, wqkv_b, nullptr, nullptr, nullptr, nullptr, qbuf, kbuf, vtbuf);

  attn_k<<<256, 512, 0, stream>>>(qbuf, kbuf, vtbuf, obuf);

  gemm_bt_k<MODE_RES><<<dim3(64, 4), 256, 0, stream>>>(
      obuf, wo_b, nullptr, x1, x2, nullptr, nullptr, nullptr, nullptr);

  rmsnorm_k<false><<<ROWS, 256, 0, stream>>>(x2, n2g, n2b, nullptr, hbuf);

  gemm_bt_k<MODE_BIAS><<<dim3(64, 4), 256, 0, stream>>>(
      hbuf, w1_b, b1, nullptr, x1, nullptr, nullptr, nullptr, nullptr);

  rmsnorm_k<false><<<ROWS, 256, 0, stream>>>(x1, ffg, ffb, nullptr, hbuf);

  gemm_bt_k<MODE_BIAS><<<dim3(64, 4), 256, 0, stream>>>(
      hbuf, sw_b16, swb, nullptr, x1, nullptr, nullptr, nullptr, nullptr);

  gemm_bt_k<MODE_SWIGLU><<<dim3(64, 4), 256, 0, stream>>>(
      hbuf, sw_b16 + 512 * 512, swb + 512, x1, nullptr, qbuf,
      nullptr, nullptr, nullptr);

  gemm_bt_k<MODE_RESBIAS><<<dim3(64, 4), 256, 0, stream>>>(
      qbuf, w2_b, b2, x2, out, nullptr, nullptr, nullptr, nullptr);
}

// Round 3
// 226.427 us; speedup vs baseline: 1.6823x; 1.1423x over previous
//
#include <hip/hip_runtime.h>
#include <hip/hip_bf16.h>
#include <cstdint>
#include <cstddef>

typedef __bf16 bf16;
typedef __bf16 bf16x4_t __attribute__((ext_vector_type(4)));
typedef __bf16 bf16x8_t __attribute__((ext_vector_type(8)));
typedef float f32x4 __attribute__((ext_vector_type(4)));
typedef float f32x16 __attribute__((ext_vector_type(16)));

#define DEV_INLINE __device__ __forceinline__

constexpr int SEQ = 2048, DIM = 512, HEADS = 8, DH = 64;
constexpr int ROWS = 4 * SEQ;                     // 8192
constexpr float EPSF = 1.1920928955078125e-07f;   // np.finfo(float32).eps
constexpr float RSQRT_DIM = 0.04419417382415922f; // 512^-0.5

// ---------------- global->LDS direct (16B per lane) ----------------
DEV_INLINE void load_lds16(const void* g, void* l) {
  __builtin_amdgcn_global_load_lds(
      (const __attribute__((address_space(1))) void*)g,
      (__attribute__((address_space(3))) void*)l,
      16, 0, 0);
}

DEV_INLINE unsigned int packbf(float a, float b) {
  union { unsigned int u; bf16 h[2]; } z;
  z.h[0] = (bf16)a;
  z.h[1] = (bf16)b;
  return z.u;
}

// ---------------- fused fp32 -> bf16 weight convert (all weights, 1 launch) --
// float4-index segments: wq|wk|wv|wo|w1|sww(2x)|w2 -> contiguous bf16 dst
__global__ __launch_bounds__(256) void cvt_all_k(
    const float* __restrict__ wq, const float* __restrict__ wk,
    const float* __restrict__ wv, const float* __restrict__ wo,
    const float* __restrict__ w1, const float* __restrict__ sww,
    const float* __restrict__ w2, bf16* __restrict__ dst) {
  const int i = blockIdx.x * 256 + threadIdx.x;  // 0..524287
  const float* src;
  int local;
  if (i < 196608)      { src = (i < 65536) ? wq : (i < 131072) ? wk : wv; local = i & 65535; }
  else if (i < 262144) { src = wo;  local = i - 196608; }
  else if (i < 327680) { src = w1;  local = i - 262144; }
  else if (i < 458752) { src = sww; local = i - 327680; }
  else                 { src = w2;  local = i - 458752; }
  float4 f = reinterpret_cast<const float4*>(src)[local];
  bf16x4_t o;
  o[0] = (bf16)f.x; o[1] = (bf16)f.y; o[2] = (bf16)f.z; o[3] = (bf16)f.w;
  reinterpret_cast<bf16x4_t*>(dst)[i] = o;
}

// ---------------- RMSNorm (vectorized float4; 2 rows per block) ----------
template <bool ADDPOS>
__global__ __launch_bounds__(256) void rmsnorm_k(const float* __restrict__ in,
                                                 const float* __restrict__ gain,
                                                 const float* __restrict__ bias,
                                                 float* __restrict__ outF,
                                                 bf16* __restrict__ outB) {
  const int sub = threadIdx.x >> 7;              // row within block
  const int row = blockIdx.x * 2 + sub;
  const int t = threadIdx.x & 127;               // cols 4t..4t+3
  const float* rp = in + (size_t)row * DIM;
  float4 v = reinterpret_cast<const float4*>(rp)[t];
  if constexpr (ADDPOS) {
    const int s = row & (SEQ - 1);
    const float e0 = (float)(4 * t) * (1.0f / (float)DIM);
    const float e1 = (float)(4 * t + 2) * (1.0f / (float)DIM);
    const float d0 = 1.0f / (powf(10000.0f, e0) + EPSF);
    const float d1 = 1.0f / (powf(10000.0f, e1) + EPSF);
    const float a0 = (float)s * d0, a1 = (float)s * d1;
    v.x += sinf(a0); v.y += cosf(a0);
    v.z += sinf(a1); v.w += cosf(a1);
  }
  float ss = v.x * v.x + v.y * v.y + v.z * v.z + v.w * v.w;
#pragma unroll
  for (int off = 32; off > 0; off >>= 1) ss += __shfl_down(ss, off, 64);
  __shared__ float red[4];
  const int wv = threadIdx.x >> 6;
  if ((threadIdx.x & 63) == 0) red[wv] = ss;
  __syncthreads();
  const float total = red[sub * 2] + red[sub * 2 + 1];
  const float scale = sqrtf(total) * RSQRT_DIM;
  const float inv = 1.0f / (scale + EPSF);
  if constexpr (ADDPOS)
    reinterpret_cast<float4*>(outF + (size_t)row * DIM)[t] = v;
  const float4 g = reinterpret_cast<const float4*>(gain)[t];
  const float4 bb = reinterpret_cast<const float4*>(bias)[t];
  bf16x4_t o;
  o[0] = (bf16)(v.x * inv * g.x + bb.x);
  o[1] = (bf16)(v.y * inv * g.y + bb.y);
  o[2] = (bf16)(v.z * inv * g.z + bb.z);
  o[3] = (bf16)(v.w * inv * g.w + bb.w);
  reinterpret_cast<bf16x4_t*>(outB + (size_t)row * DIM)[t] = o;
}

// ---------------- GEMM: C[M,N] = A[M,512] @ Bt[N,512]^T, bf16 in, f32 acc ---
// BM=BN=128, BK=32, 256 threads (2x2 waves, 64x64/wave). 3-stage pipelined
// staging: stage kt+2 while computing kt; counted vmcnt(4); raw s_barrier.
enum { MODE_QKV = 0, MODE_RES = 1, MODE_BIAS = 2, MODE_SWIGLU = 3, MODE_RESBIAS = 4 };

template <int MODE>
__global__ __launch_bounds__(256) void gemm_bt_k(
    const bf16* __restrict__ A, const bf16* __restrict__ Bt,
    const float* __restrict__ bias, const float* __restrict__ res,
    float* __restrict__ outF, bf16* __restrict__ outB,
    bf16* __restrict__ oq, bf16* __restrict__ okk, bf16* __restrict__ ovT) {
  __shared__ __align__(16) bf16 sA[3][128 * 32];
  __shared__ __align__(16) bf16 sB[3][128 * 32];
  const int tid = threadIdx.x;
  const int wave = tid >> 6, lane = tid & 63;
  const int m0 = blockIdx.x * 128, n0 = blockIdx.y * 128;
  const int wm = wave >> 1, wn = wave & 1;
  const int lr = lane & 15, lk = (lane >> 4) * 8;

  const f32x4 fzero = {0.f, 0.f, 0.f, 0.f};
  f32x4 acc[4][4];
#pragma unroll
  for (int i = 0; i < 4; ++i)
#pragma unroll
    for (int j = 0; j < 4; ++j) acc[i][j] = fzero;

  const int off0 = wave * 1024 + lane * 16;

  auto stage = [&](int buf, int kt) {
    const int k0 = kt * 32;
#pragma unroll
    for (int part = 0; part < 2; ++part) {
      const int off = part * 4096 + off0;
      const int row = off >> 6, colb = off & 63;
      load_lds16((const char*)A + ((size_t)(m0 + row) * 512 + k0) * 2 + colb,
                 (char*)&sA[buf][0] + part * 4096 + wave * 1024);
      load_lds16((const char*)Bt + ((size_t)(n0 + row) * 512 + k0) * 2 + colb,
                 (char*)&sB[buf][0] + part * 4096 + wave * 1024);
    }
  };

  stage(0, 0);
  stage(1, 1);
  asm volatile("s_waitcnt vmcnt(4)\ns_barrier" ::: "memory");

#pragma unroll
  for (int kt = 0; kt < 16; ++kt) {
    const int cur = kt % 3;
    if (kt + 2 < 16) stage((kt + 2) % 3, kt + 2);
    bf16x8_t af[4], bfr[4];
#pragma unroll
    for (int mf = 0; mf < 4; ++mf)
      af[mf] = *(const bf16x8_t*)(&sA[cur][0] + (wm * 64 + mf * 16 + lr) * 32 + lk);
#pragma unroll
    for (int nf = 0; nf < 4; ++nf)
      bfr[nf] = *(const bf16x8_t*)(&sB[cur][0] + (wn * 64 + nf * 16 + lr) * 32 + lk);
    // drain ds_reads into regs before the rotation barrier (race-free reuse)
    asm volatile("s_waitcnt lgkmcnt(0)" ::: "memory");
#pragma unroll
    for (int mf = 0; mf < 4; ++mf)
#pragma unroll
      for (int nf = 0; nf < 4; ++nf)
        acc[mf][nf] = __builtin_amdgcn_mfma_f32_16x16x32_bf16(af[mf], bfr[nf],
                                                              acc[mf][nf], 0, 0, 0);
    if (kt < 14)      asm volatile("s_waitcnt vmcnt(4)\ns_barrier" ::: "memory");
    else if (kt < 15) asm volatile("s_waitcnt vmcnt(0)\ns_barrier" ::: "memory");
  }

  const int rbase = m0 + wm * 64 + (lane >> 4) * 4;
  const int cbase = n0 + wn * 64 + lr;
#pragma unroll
  for (int mf = 0; mf < 4; ++mf) {
#pragma unroll
    for (int nf = 0; nf < 4; ++nf) {
      const int c = cbase + nf * 16;
#pragma unroll
      for (int rg = 0; rg < 4; ++rg) {
        const int r = rbase + mf * 16 + rg;
        float v = acc[mf][nf][rg];
        if constexpr (MODE == MODE_QKV) {
          const int which = c >> 9, cc = c & 511;
          const int b = r >> 11, s = r & 2047;
          const int h = cc >> 6, dh = cc & 63;
          const size_t bh = (size_t)(b * HEADS + h);
          if (which == 0)      oq [(bh * SEQ + s) * DH + dh] = (bf16)(v * RSQRT_DIM);
          else if (which == 1) okk[(bh * SEQ + s) * DH + dh] = (bf16)v;
          else                 ovT[(bh * DH + dh) * SEQ + s] = (bf16)v;  // V^T
        } else if constexpr (MODE == MODE_RES) {
          const size_t idx = (size_t)r * 512 + c;
          outF[idx] = res[idx] + v;
        } else if constexpr (MODE == MODE_BIAS) {
          const size_t idx = (size_t)r * 512 + c;
          outF[idx] = v + bias[c];
        } else if constexpr (MODE == MODE_SWIGLU) {
          const size_t idx = (size_t)r * 512 + c;
          float u1 = res[idx];
          float sig = 1.0f / (1.0f + __expf(-u1));
          outB[idx] = (bf16)(u1 * sig + v + bias[c]);
        } else {
          const size_t idx = (size_t)r * 512 + c;
          outF[idx] = res[idx] + v + bias[c];
        }
      }
    }
  }
}

// ---------------- causal flash attention, swapped-QK^T 32x32 ----------------
// 256 blocks x 512 threads; wave owns 32 q-rows. K register ping-pong
// (prefetch kt+1 during compute of kt); V loaded right after QK (latency
// hidden under softmax). In-register softmax; P packed via shfl_xor(32).
struct K8 { bf16x8_t r[8]; };

__global__ __launch_bounds__(512) void attn_k(const bf16* __restrict__ Q,
                                              const bf16* __restrict__ K,
                                              const bf16* __restrict__ VT,
                                              bf16* __restrict__ O) {
  const int tid = threadIdx.x;
  const int wave = tid >> 6, lane = tid & 63;
  const int lq = lane & 31, hi = lane >> 5;

  const int wg = blockIdx.x;
  const int xcd = wg & 7, slot = wg >> 3;
  const int bh = xcd * 4 + (slot >> 3);
  const int ip = slot & 7;
  const int tile = (wave < 4) ? ip : (15 - ip);
  const int qw = tile * 128 + (wave & 3) * 32;

  const bf16* Qb = Q + (size_t)bh * SEQ * DH;
  const bf16* Kb = K + (size_t)bh * SEQ * DH;
  const bf16* Vb = VT + (size_t)bh * DH * SEQ;

  __shared__ __align__(16) bf16 olds[8][32][80];

  bf16x8_t qf[4];
  {
    const bf16* qp = Qb + (size_t)(qw + lq) * DH + 8 * hi;
    qf[0] = *(const bf16x8_t*)(qp);
    qf[1] = *(const bf16x8_t*)(qp + 16);
    qf[2] = *(const bf16x8_t*)(qp + 32);
    qf[3] = *(const bf16x8_t*)(qp + 48);
  }

  f32x16 oa0, oa1;
#pragma unroll
  for (int r = 0; r < 16; ++r) { oa0[r] = 0.f; oa1[r] = 0.f; }
  float mrun = -3.0e38f, lrun = 0.f;

  auto loadK = [&](int kt, K8& kk) {
    const bf16* kp = Kb + (size_t)(kt * 64 + lq) * DH + 8 * hi;
    kk.r[0] = *(const bf16x8_t*)(kp);
    kk.r[1] = *(const bf16x8_t*)(kp + 16);
    kk.r[2] = *(const bf16x8_t*)(kp + 32);
    kk.r[3] = *(const bf16x8_t*)(kp + 48);
    const bf16* kp1 = kp + 32 * DH;
    kk.r[4] = *(const bf16x8_t*)(kp1);
    kk.r[5] = *(const bf16x8_t*)(kp1 + 16);
    kk.r[6] = *(const bf16x8_t*)(kp1 + 32);
    kk.r[7] = *(const bf16x8_t*)(kp1 + 48);
  };

  auto compute = [&](int kt, const K8& kk, bool last) {
    f32x16 s0, s1;
#pragma unroll
    for (int r = 0; r < 16; ++r) { s0[r] = 0.f; s1[r] = 0.f; }
    __builtin_amdgcn_s_setprio(1);
#pragma unroll
    for (int s = 0; s < 4; ++s) {
      s0 = __builtin_amdgcn_mfma_f32_32x32x16_bf16(kk.r[s],     qf[s], s0, 0, 0, 0);
      s1 = __builtin_amdgcn_mfma_f32_32x32x16_bf16(kk.r[s + 4], qf[s], s1, 0, 0, 0);
    }
    __builtin_amdgcn_s_setprio(0);

    // V tile loads issued now; consumed after softmax (latency hidden)
    K8 vv;
    {
      const bf16* vp = Vb + (size_t)lq * SEQ + kt * 64 + 8 * hi;
      vv.r[0] = *(const bf16x8_t*)(vp);
      vv.r[1] = *(const bf16x8_t*)(vp + 16);
      vv.r[2] = *(const bf16x8_t*)(vp + 32);
      vv.r[3] = *(const bf16x8_t*)(vp + 48);
      const bf16* vp1 = vp + 32 * SEQ;
      vv.r[4] = *(const bf16x8_t*)(vp1);
      vv.r[5] = *(const bf16x8_t*)(vp1 + 16);
      vv.r[6] = *(const bf16x8_t*)(vp1 + 32);
      vv.r[7] = *(const bf16x8_t*)(vp1 + 48);
    }

    const int qg = qw + lq;
    float mt = -3.0e38f;
#pragma unroll
    for (int r = 0; r < 16; ++r) {
      float a = s0[r], b = s1[r];
      if (last) {
        const int kl = kt * 64 + (r & 3) + 8 * (r >> 2) + 4 * hi;
        if (kl > qg) a = -3.0e38f;
        if (kl + 32 > qg) b = -3.0e38f;
        s0[r] = a; s1[r] = b;
      }
      mt = fmaxf(mt, fmaxf(a, b));
    }
    mt = fmaxf(mt, __shfl_xor(mt, 32));
    const float mnew = fmaxf(mrun, mt);
    const float alpha = __expf(mrun - mnew);
    mrun = mnew;

    float sum = 0.f;
#pragma unroll
    for (int r = 0; r < 16; ++r) {
      float a = __expf(s0[r] - mnew); s0[r] = a; sum += a;
      float b = __expf(s1[r] - mnew); s1[r] = b; sum += b;
    }
    sum += __shfl_xor(sum, 32);
    lrun = lrun * alpha + sum;

#pragma unroll
    for (int r = 0; r < 16; ++r) { oa0[r] *= alpha; oa1[r] *= alpha; }

    unsigned int wa0[4], wb0[4], wa1[4], wb1[4];
#pragma unroll
    for (int t = 0; t < 4; ++t) {
      wa0[t] = packbf(s0[4 * t], s0[4 * t + 1]);
      wb0[t] = packbf(s0[4 * t + 2], s0[4 * t + 3]);
      wa1[t] = packbf(s1[4 * t], s1[4 * t + 1]);
      wb1[t] = packbf(s1[4 * t + 2], s1[4 * t + 3]);
    }
    unsigned int xa0[4], xb0[4], xa1[4], xb1[4];
#pragma unroll
    for (int t = 0; t < 4; ++t) {
      xa0[t] = __shfl_xor((int)wa0[t], 32);
      xb0[t] = __shfl_xor((int)wb0[t], 32);
      xa1[t] = __shfl_xor((int)wa1[t], 32);
      xb1[t] = __shfl_xor((int)wb1[t], 32);
    }
    union U8 { unsigned int u[4]; bf16x8_t v; };
    U8 p00, p01, p10, p11;
    p00.u[0] = hi ? xa0[1] : wa0[0]; p00.u[1] = hi ? xb0[1] : wb0[0];
    p00.u[2] = hi ? wa0[1] : xa0[0]; p00.u[3] = hi ? wb0[1] : xb0[0];
    p01.u[0] = hi ? xa0[3] : wa0[2]; p01.u[1] = hi ? xb0[3] : wb0[2];
    p01.u[2] = hi ? wa0[3] : xa0[2]; p01.u[3] = hi ? wb0[3] : xb0[2];
    p10.u[0] = hi ? xa1[1] : wa1[0]; p10.u[1] = hi ? xb1[1] : wb1[0];
    p10.u[2] = hi ? wa1[1] : xa1[0]; p10.u[3] = hi ? wb1[1] : xb1[0];
    p11.u[0] = hi ? xa1[3] : wa1[2]; p11.u[1] = hi ? xb1[3] : wb1[2];
    p11.u[2] = hi ? wa1[3] : xa1[2]; p11.u[3] = hi ? wb1[3] : xb1[2];

    __builtin_amdgcn_s_setprio(1);
    oa0 = __builtin_amdgcn_mfma_f32_32x32x16_bf16(vv.r[0], p00.v, oa0, 0, 0, 0);
    oa0 = __builtin_amdgcn_mfma_f32_32x32x16_bf16(vv.r[1], p01.v, oa0, 0, 0, 0);
    oa0 = __builtin_amdgcn_mfma_f32_32x32x16_bf16(vv.r[2], p10.v, oa0, 0, 0, 0);
    oa0 = __builtin_amdgcn_mfma_f32_32x32x16_bf16(vv.r[3], p11.v, oa0, 0, 0, 0);
    oa1 = __builtin_amdgcn_mfma_f32_32x32x16_bf16(vv.r[4], p00.v, oa1, 0, 0, 0);
    oa1 = __builtin_amdgcn_mfma_f32_32x32x16_bf16(vv.r[5], p01.v, oa1, 0, 0, 0);
    oa1 = __builtin_amdgcn_mfma_f32_32x32x16_bf16(vv.r[6], p10.v, oa1, 0, 0, 0);
    oa1 = __builtin_amdgcn_mfma_f32_32x32x16_bf16(vv.r[7], p11.v, oa1, 0, 0, 0);
    __builtin_amdgcn_s_setprio(0);
  };

  const int nkt = (qw >> 6) + 1;
  K8 kA, kB;
  loadK(0, kA);
  int kt = 0;
  for (;;) {
    if (kt + 1 < nkt) loadK(kt + 1, kB);
    if (kt + 1 >= nkt) { compute(kt, kA, true); break; }
    compute(kt, kA, false);
    ++kt;
    if (kt + 1 < nkt) loadK(kt + 1, kA);
    if (kt + 1 >= nkt) { compute(kt, kB, true); break; }
    compute(kt, kB, false);
    ++kt;
  }

  // ---- epilogue: /l, transpose through LDS, coalesced store ----
  const float inv = 1.0f / lrun;
  bf16* ol = &olds[wave][0][0];  // [32][80]
#pragma unroll
  for (int t = 0; t < 4; ++t) {
    const int d0 = 8 * t + 4 * hi;
    *(unsigned int*)(ol + lq * 80 + d0) =
        packbf(oa0[4 * t] * inv, oa0[4 * t + 1] * inv);
    *(unsigned int*)(ol + lq * 80 + d0 + 2) =
        packbf(oa0[4 * t + 2] * inv, oa0[4 * t + 3] * inv);
    *(unsigned int*)(ol + lq * 80 + 32 + d0) =
        packbf(oa1[4 * t] * inv, oa1[4 * t + 1] * inv);
    *(unsigned int*)(ol + lq * 80 + 32 + d0 + 2) =
        packbf(oa1[4 * t + 2] * inv, oa1[4 * t + 3] * inv);
  }
  const int b = bh >> 3, h = bh & 7;
#pragma unroll
  for (int ps = 0; ps < 4; ++ps) {
    const int flat = ps * 1024 + lane * 16;
    const int qr = flat >> 7, off = flat & 127;
    bf16x8_t vvv = *(const bf16x8_t*)((const char*)ol + qr * 160 + off);
    *(bf16x8_t*)(O + ((size_t)(b * SEQ + qw + qr)) * DIM + h * 64 + off / 2) = vvv;
  }
}

// ---------------- host launcher ----------------
extern "C" void kernel_launch(void* const* d_in, const int* in_sizes, int n_in,
                              void* d_out, int out_size, void* d_ws, size_t ws_size,
                              hipStream_t stream) {
  const float* x   = (const float*)d_in[0];
  const float* n1g = (const float*)d_in[1];
  const float* n1b = (const float*)d_in[2];
  const float* wq  = (const float*)d_in[3];
  const float* wk  = (const float*)d_in[4];
  const float* wv  = (const float*)d_in[5];
  const float* wo  = (const float*)d_in[6];
  const float* n2g = (const float*)d_in[7];
  const float* n2b = (const float*)d_in[8];
  const float* w1  = (const float*)d_in[9];
  const float* b1  = (const float*)d_in[10];
  const float* ffg = (const float*)d_in[11];
  const float* ffb = (const float*)d_in[12];
  const float* sww = (const float*)d_in[13];
  const float* swb = (const float*)d_in[14];
  const float* w2  = (const float*)d_in[15];
  const float* b2  = (const float*)d_in[16];
  float* out = (float*)d_out;

  char* ws = (char*)d_ws;
  float* x1 = (float*)(ws + 0);            // 16 MiB
  float* x2 = (float*)(ws + 16777216);     // 16 MiB
  bf16* hbuf   = (bf16*)(ws + 33554432);   // 8 MiB
  bf16* qbuf   = (bf16*)(ws + 41943040);   // 8 MiB
  bf16* kbuf   = (bf16*)(ws + 50331648);   // 8 MiB
  bf16* vtbuf  = (bf16*)(ws + 58720256);   // 8 MiB (V^T)
  bf16* obuf   = (bf16*)(ws + 67108864);   // 8 MiB
  bf16* wbase  = (bf16*)(ws + 75497472);   // 4 MiB contiguous bf16 weights
  bf16* wqkv_b = wbase;                    // [1536][512]
  bf16* wo_b   = wbase + 786432;
  bf16* w1_b   = wbase + 1048576;
  bf16* sw_b16 = wbase + 1310720;          // [1024][512]
  bf16* w2_b   = wbase + 1835008;

  cvt_all_k<<<2048, 256, 0, stream>>>(wq, wk, wv, wo, w1, sww, w2, wbase);

  rmsnorm_k<true><<<ROWS / 2, 256, 0, stream>>>(x, n1g, n1b, x1, hbuf);

  gemm_bt_k<MODE_QKV><<<dim3(64, 12), 256, 0, stream>>>(
      hbuf, wqkv_b, nullptr, nullptr, nullptr, nullptr, qbuf, kbuf, vtbuf);

  attn_k<<<256, 512, 0, stream>>>(qbuf, kbuf, vtbuf, obuf);

  gemm_bt_k<MODE_RES><<<dim3(64, 4), 256, 0, stream>>>(
      obuf, wo_b, nullptr, x1, x2, nullptr, nullptr, nullptr, nullptr);

  rmsnorm_k<false><<<ROWS / 2, 256, 0, stream>>>(x2, n2g, n2b, nullptr, hbuf);

  gemm_bt_k<MODE_BIAS><<<dim3(64, 4), 256, 0, stream>>>(
      hbuf, w1_b, b1, nullptr, x1, nullptr, nullptr, nullptr, nullptr);

  rmsnorm_k<false><<<ROWS / 2, 256, 0, stream>>>(x1, ffg, ffb, nullptr, hbuf);

  gemm_bt_k<MODE_BIAS><<<dim3(64, 4), 256, 0, stream>>>(
      hbuf, sw_b16, swb, nullptr, x1, nullptr, nullptr, nullptr, nullptr);

  gemm_bt_k<MODE_SWIGLU><<<dim3(64, 4), 256, 0, stream>>>(
      hbuf, sw_b16 + 512 * 512, swb + 512, x1, nullptr, qbuf,
      nullptr, nullptr, nullptr);

  gemm_bt_k<MODE_RESBIAS><<<dim3(64, 4), 256, 0, stream>>>(
      qbuf, w2_b, b2, x2, out, nullptr, nullptr, nullptr, nullptr);
}

// Round 4
// 209.668 us; speedup vs baseline: 1.8168x; 1.0799x over previous
//
#include <hip/hip_runtime.h>
#include <hip/hip_bf16.h>
#include <cstdint>
#include <cstddef>

typedef __bf16 bf16;
typedef __bf16 bf16x4_t __attribute__((ext_vector_type(4)));
typedef __bf16 bf16x8_t __attribute__((ext_vector_type(8)));
typedef float f32x4 __attribute__((ext_vector_type(4)));
typedef float f32x16 __attribute__((ext_vector_type(16)));

#define DEV_INLINE __device__ __forceinline__

constexpr int SEQ = 2048, DIM = 512, HEADS = 8, DH = 64;
constexpr int ROWS = 4 * SEQ;                     // 8192
constexpr float EPSF = 1.1920928955078125e-07f;   // np.finfo(float32).eps
constexpr float RSQRT_DIM = 0.04419417382415922f; // 512^-0.5
constexpr float LOG2E = 1.44269504088896f;

// ---------------- global->LDS direct (16B per lane) ----------------
DEV_INLINE void load_lds16(const void* g, void* l) {
  __builtin_amdgcn_global_load_lds(
      (const __attribute__((address_space(1))) void*)g,
      (__attribute__((address_space(3))) void*)l,
      16, 0, 0);
}

DEV_INLINE unsigned int packbf(float a, float b) {
  union { unsigned int u; bf16 h[2]; } z;
  z.h[0] = (bf16)a;
  z.h[1] = (bf16)b;
  return z.u;
}

// ---------------- fused fp32 -> bf16 weight convert (1 launch) ----------
__global__ __launch_bounds__(256) void cvt_all_k(
    const float* __restrict__ wq, const float* __restrict__ wk,
    const float* __restrict__ wv, const float* __restrict__ wo,
    const float* __restrict__ w1, const float* __restrict__ sww,
    const float* __restrict__ w2, bf16* __restrict__ dst) {
  const int i = blockIdx.x * 256 + threadIdx.x;  // 0..524287
  const float* src;
  int local;
  if (i < 196608)      { src = (i < 65536) ? wq : (i < 131072) ? wk : wv; local = i & 65535; }
  else if (i < 262144) { src = wo;  local = i - 196608; }
  else if (i < 327680) { src = w1;  local = i - 262144; }
  else if (i < 458752) { src = sww; local = i - 327680; }
  else                 { src = w2;  local = i - 458752; }
  float4 f = reinterpret_cast<const float4*>(src)[local];
  bf16x4_t o;
  o[0] = (bf16)f.x; o[1] = (bf16)f.y; o[2] = (bf16)f.z; o[3] = (bf16)f.w;
  reinterpret_cast<bf16x4_t*>(dst)[i] = o;
}

// ---------------- RMSNorm (float4 vectorized; 2 rows per block) ----------
template <bool ADDPOS>
__global__ __launch_bounds__(256) void rmsnorm_k(const float* __restrict__ in,
                                                 const float* __restrict__ gain,
                                                 const float* __restrict__ bias,
                                                 float* __restrict__ outF,
                                                 bf16* __restrict__ outB) {
  const int sub = threadIdx.x >> 7;
  const int row = blockIdx.x * 2 + sub;
  const int t = threadIdx.x & 127;
  const float* rp = in + (size_t)row * DIM;
  float4 v = reinterpret_cast<const float4*>(rp)[t];
  if constexpr (ADDPOS) {
    const int s = row & (SEQ - 1);
    const float e0 = (float)(4 * t) * (1.0f / (float)DIM);
    const float e1 = (float)(4 * t + 2) * (1.0f / (float)DIM);
    const float d0 = 1.0f / (powf(10000.0f, e0) + EPSF);
    const float d1 = 1.0f / (powf(10000.0f, e1) + EPSF);
    const float a0 = (float)s * d0, a1 = (float)s * d1;
    v.x += sinf(a0); v.y += cosf(a0);
    v.z += sinf(a1); v.w += cosf(a1);
  }
  float ss = v.x * v.x + v.y * v.y + v.z * v.z + v.w * v.w;
#pragma unroll
  for (int off = 32; off > 0; off >>= 1) ss += __shfl_down(ss, off, 64);
  __shared__ float red[4];
  const int wv = threadIdx.x >> 6;
  if ((threadIdx.x & 63) == 0) red[wv] = ss;
  __syncthreads();
  const float total = red[sub * 2] + red[sub * 2 + 1];
  const float scale = sqrtf(total) * RSQRT_DIM;
  const float inv = 1.0f / (scale + EPSF);
  if constexpr (ADDPOS)
    reinterpret_cast<float4*>(outF + (size_t)row * DIM)[t] = v;
  const float4 g = reinterpret_cast<const float4*>(gain)[t];
  const float4 bb = reinterpret_cast<const float4*>(bias)[t];
  bf16x4_t o;
  o[0] = (bf16)(v.x * inv * g.x + bb.x);
  o[1] = (bf16)(v.y * inv * g.y + bb.y);
  o[2] = (bf16)(v.z * inv * g.z + bb.z);
  o[3] = (bf16)(v.w * inv * g.w + bb.w);
  reinterpret_cast<bf16x4_t*>(outB + (size_t)row * DIM)[t] = o;
}

// ---------------- GEMM: C[M,N] = A[M,512] @ Bt[N,512]^T ----------------
// BM=128, BN=64, BK=32; 256 thr (2x2 waves, 64x32/wave). 3-stage pipeline.
// MODE_SWIGLU2 stages two weight halves (sw1, sw2) and computes both.
enum { MODE_QKV = 0, MODE_RES = 1, MODE_BIAS = 2, MODE_SWIGLU2 = 3, MODE_RESBIAS = 4 };

template <int MODE>
__global__ __launch_bounds__(256) void gemm_bt_k(
    const bf16* __restrict__ A, const bf16* __restrict__ Bt,
    const float* __restrict__ bias, const float* __restrict__ res,
    float* __restrict__ outF, bf16* __restrict__ outB,
    bf16* __restrict__ oq, bf16* __restrict__ okk, bf16* __restrict__ ovT) {
  constexpr int BELEMS = (MODE == MODE_SWIGLU2) ? 4096 : 2048;
  __shared__ __align__(16) bf16 sA[3][128 * 32];
  __shared__ __align__(16) bf16 sB[3][BELEMS];
  const int tid = threadIdx.x;
  const int wave = tid >> 6, lane = tid & 63;
  const int m0 = blockIdx.x * 128, n0 = blockIdx.y * 64;
  const int wm = wave >> 1, wn = wave & 1;
  const int lr = lane & 15, lk = (lane >> 4) * 8;

  const f32x4 fzero = {0.f, 0.f, 0.f, 0.f};
  f32x4 acc[4][2], acc2[4][2];
#pragma unroll
  for (int i = 0; i < 4; ++i)
#pragma unroll
    for (int j = 0; j < 2; ++j) { acc[i][j] = fzero; acc2[i][j] = fzero; }

  const int off0 = wave * 1024 + lane * 16;
  const int rowS = off0 >> 6, colb = off0 & 63;

  auto stage = [&](int buf, int kt) {
    const int k0 = kt * 32;
    load_lds16((const char*)A + ((size_t)(m0 + rowS) * 512 + k0) * 2 + colb,
               (char*)&sA[buf][0] + off0);
    load_lds16((const char*)A + ((size_t)(m0 + 64 + rowS) * 512 + k0) * 2 + colb,
               (char*)&sA[buf][0] + 4096 + off0);
    load_lds16((const char*)Bt + ((size_t)(n0 + rowS) * 512 + k0) * 2 + colb,
               (char*)&sB[buf][0] + off0);
    if constexpr (MODE == MODE_SWIGLU2)
      load_lds16((const char*)Bt + ((size_t)(512 + n0 + rowS) * 512 + k0) * 2 + colb,
                 (char*)&sB[buf][0] + 4096 + off0);
  };

  stage(0, 0);
  stage(1, 1);
  if constexpr (MODE == MODE_SWIGLU2)
    asm volatile("s_waitcnt vmcnt(4)\ns_barrier" ::: "memory");
  else
    asm volatile("s_waitcnt vmcnt(3)\ns_barrier" ::: "memory");

#pragma unroll
  for (int kt = 0; kt < 16; ++kt) {
    const int cur = kt % 3;
    if (kt + 2 < 16) stage((kt + 2) % 3, kt + 2);
    bf16x8_t af[4], bfr[2], bfr2[2];
#pragma unroll
    for (int mf = 0; mf < 4; ++mf)
      af[mf] = *(const bf16x8_t*)(&sA[cur][0] + (wm * 64 + mf * 16 + lr) * 32 + lk);
#pragma unroll
    for (int nf = 0; nf < 2; ++nf)
      bfr[nf] = *(const bf16x8_t*)(&sB[cur][0] + (wn * 32 + nf * 16 + lr) * 32 + lk);
    if constexpr (MODE == MODE_SWIGLU2) {
#pragma unroll
      for (int nf = 0; nf < 2; ++nf)
        bfr2[nf] = *(const bf16x8_t*)(&sB[cur][0] + 2048 + (wn * 32 + nf * 16 + lr) * 32 + lk);
    }
    asm volatile("s_waitcnt lgkmcnt(0)" ::: "memory");
#pragma unroll
    for (int mf = 0; mf < 4; ++mf)
#pragma unroll
      for (int nf = 0; nf < 2; ++nf) {
        acc[mf][nf] = __builtin_amdgcn_mfma_f32_16x16x32_bf16(af[mf], bfr[nf],
                                                              acc[mf][nf], 0, 0, 0);
        if constexpr (MODE == MODE_SWIGLU2)
          acc2[mf][nf] = __builtin_amdgcn_mfma_f32_16x16x32_bf16(af[mf], bfr2[nf],
                                                                 acc2[mf][nf], 0, 0, 0);
      }
    if (kt < 14) {
      if constexpr (MODE == MODE_SWIGLU2)
        asm volatile("s_waitcnt vmcnt(4)\ns_barrier" ::: "memory");
      else
        asm volatile("s_waitcnt vmcnt(3)\ns_barrier" ::: "memory");
    } else if (kt < 15) {
      asm volatile("s_waitcnt vmcnt(0)\ns_barrier" ::: "memory");
    }
  }

  const int rbase = m0 + wm * 64 + (lane >> 4) * 4;
  const int cbase = n0 + wn * 32 + lr;
#pragma unroll
  for (int mf = 0; mf < 4; ++mf) {
#pragma unroll
    for (int nf = 0; nf < 2; ++nf) {
      const int c = cbase + nf * 16;
#pragma unroll
      for (int rg = 0; rg < 4; ++rg) {
        const int r = rbase + mf * 16 + rg;
        float v = acc[mf][nf][rg];
        if constexpr (MODE == MODE_QKV) {
          const int which = c >> 9, cc = c & 511;
          const int b = r >> 11, s = r & 2047;
          const int h = cc >> 6, dh = cc & 63;
          const size_t bh = (size_t)(b * HEADS + h);
          if (which == 0)      oq [(bh * SEQ + s) * DH + dh] = (bf16)(v * RSQRT_DIM * LOG2E);
          else if (which == 1) okk[(bh * SEQ + s) * DH + dh] = (bf16)v;
          else                 ovT[(bh * DH + dh) * SEQ + s] = (bf16)v;  // V^T
        } else if constexpr (MODE == MODE_RES) {
          const size_t idx = (size_t)r * 512 + c;
          outF[idx] = res[idx] + v;
        } else if constexpr (MODE == MODE_BIAS) {
          const size_t idx = (size_t)r * 512 + c;
          outF[idx] = v + bias[c];
        } else if constexpr (MODE == MODE_SWIGLU2) {
          const size_t idx = (size_t)r * 512 + c;
          const float u1 = v + bias[c];
          const float u2 = acc2[mf][nf][rg] + bias[512 + c];
          const float sig = 1.0f / (1.0f + __expf(-u1));
          outB[idx] = (bf16)(u1 * sig + u2);
        } else {
          const size_t idx = (size_t)r * 512 + c;
          outF[idx] = res[idx] + v + bias[c];
        }
      }
    }
  }
}

// ---------------- causal flash attention: split-K parity, KVBLK=32 --------
// 512 blocks x 512 thr. Block -> (xcd-local bh, 4 q-tiles of 32 rows).
// Waves (2 per tile): parity 0/1 process even/odd 32-wide k-tiles with
// independent online softmax (exp2 domain; q pre-scaled by log2e/sqrt(D));
// partials combined via LDS at the end. T13 defer-rescale. No K prefetch
// (VGPR<=128 so 2 blocks/CU co-resident -> 4 waves/SIMD TLP).
__global__ __launch_bounds__(512, 4) void attn_k(const bf16* __restrict__ Q,
                                                 const bf16* __restrict__ K,
                                                 const bf16* __restrict__ VT,
                                                 bf16* __restrict__ O) {
  const int tid = threadIdx.x;
  const int wave = tid >> 6, lane = tid & 63;
  const int lq = lane & 31, hi = lane >> 5;

  const int wg = blockIdx.x;                 // 0..511
  const int xcd = wg & 7;
  const int bh = xcd * 4 + ((wg >> 3) & 3);
  const int slot = 15 - (wg >> 5);           // long tiles dispatched first
  const int ts = wave >> 1, parity = wave & 1;
  const int t = slot * 4 + ts;               // q-tile index 0..63
  const int qw = t * 32;
  const int nkt = t + 1;                     // 32-wide k-tiles

  const bf16* Qb = Q + (size_t)bh * SEQ * DH;
  const bf16* Kb = K + (size_t)bh * SEQ * DH;
  const bf16* Vb = VT + (size_t)bh * DH * SEQ;

  __shared__ __align__(16) float cls[4][32][72];
  __shared__ float mls[4][32][2];

  bf16x8_t qf[4];
  {
    const bf16* qp = Qb + (size_t)(qw + lq) * DH + 8 * hi;
    qf[0] = *(const bf16x8_t*)(qp);
    qf[1] = *(const bf16x8_t*)(qp + 16);
    qf[2] = *(const bf16x8_t*)(qp + 32);
    qf[3] = *(const bf16x8_t*)(qp + 48);
  }

  f32x16 oa0, oa1;
#pragma unroll
  for (int r = 0; r < 16; ++r) { oa0[r] = 0.f; oa1[r] = 0.f; }
  float mrun = -3.0e38f, lrun = 0.f;

  for (int kt = parity; kt < nkt; kt += 2) {
    // ---- K fragments (k-local row = lq, dh = 16s + 8hi + j) ----
    const bf16* kp = Kb + (size_t)(kt * 32 + lq) * DH + 8 * hi;
    bf16x8_t k0 = *(const bf16x8_t*)(kp);
    bf16x8_t k1 = *(const bf16x8_t*)(kp + 16);
    bf16x8_t k2 = *(const bf16x8_t*)(kp + 32);
    bf16x8_t k3 = *(const bf16x8_t*)(kp + 48);
    f32x16 sc;
#pragma unroll
    for (int r = 0; r < 16; ++r) sc[r] = 0.f;
    __builtin_amdgcn_s_setprio(1);
    sc = __builtin_amdgcn_mfma_f32_32x32x16_bf16(k0, qf[0], sc, 0, 0, 0);
    sc = __builtin_amdgcn_mfma_f32_32x32x16_bf16(k1, qf[1], sc, 0, 0, 0);
    sc = __builtin_amdgcn_mfma_f32_32x32x16_bf16(k2, qf[2], sc, 0, 0, 0);
    sc = __builtin_amdgcn_mfma_f32_32x32x16_bf16(k3, qf[3], sc, 0, 0, 0);
    __builtin_amdgcn_s_setprio(0);

    // ---- V loads (consumed after softmax; latency hidden under it) ----
    const bf16* vp = Vb + (size_t)lq * SEQ + kt * 32 + 8 * hi;
    bf16x8_t v00 = *(const bf16x8_t*)(vp);
    bf16x8_t v01 = *(const bf16x8_t*)(vp + 16);
    const bf16* vp1 = vp + 32 * SEQ;
    bf16x8_t v10 = *(const bf16x8_t*)(vp1);
    bf16x8_t v11 = *(const bf16x8_t*)(vp1 + 16);

    // ---- causal mask (only the diagonal k-tile) ----
    if (kt == nkt - 1) {
      const int qg = qw + lq;
#pragma unroll
      for (int r = 0; r < 16; ++r) {
        const int kl = kt * 32 + (r & 3) + 8 * (r >> 2) + 4 * hi;
        if (kl > qg) sc[r] = -3.0e38f;
      }
    }

    // ---- online softmax (exp2 domain), defer-rescale (T13) ----
    float mt = -3.0e38f;
#pragma unroll
    for (int r = 0; r < 16; ++r) mt = fmaxf(mt, sc[r]);
    mt = fmaxf(mt, __shfl_xor(mt, 32));
    float mbase = mrun;
    if (!__all(mt <= mrun + 8.0f)) {
      mbase = fmaxf(mrun, mt);
      const float alpha = exp2f(mrun - mbase);
      mrun = mbase;
      lrun *= alpha;
#pragma unroll
      for (int r = 0; r < 16; ++r) { oa0[r] *= alpha; oa1[r] *= alpha; }
    }
    float sum = 0.f;
#pragma unroll
    for (int r = 0; r < 16; ++r) {
      const float e = exp2f(sc[r] - mbase);
      sc[r] = e;
      sum += e;
    }
    sum += __shfl_xor(sum, 32);
    lrun += sum;

    // ---- pack P -> PV B-fragments ----
    unsigned int wa[4], wb[4];
#pragma unroll
    for (int t4 = 0; t4 < 4; ++t4) {
      wa[t4] = packbf(sc[4 * t4], sc[4 * t4 + 1]);
      wb[t4] = packbf(sc[4 * t4 + 2], sc[4 * t4 + 3]);
    }
    unsigned int xa[4], xb[4];
#pragma unroll
    for (int t4 = 0; t4 < 4; ++t4) {
      xa[t4] = __shfl_xor((int)wa[t4], 32);
      xb[t4] = __shfl_xor((int)wb[t4], 32);
    }
    union U8 { unsigned int u[4]; bf16x8_t v; };
    U8 p0, p1;
    p0.u[0] = hi ? xa[1] : wa[0]; p0.u[1] = hi ? xb[1] : wb[0];
    p0.u[2] = hi ? wa[1] : xa[0]; p0.u[3] = hi ? wb[1] : xb[0];
    p1.u[0] = hi ? xa[3] : wa[2]; p1.u[1] = hi ? xb[3] : wb[2];
    p1.u[2] = hi ? wa[3] : xa[2]; p1.u[3] = hi ? wb[3] : xb[2];

    // ---- O^T += V^T . P ----
    __builtin_amdgcn_s_setprio(1);
    oa0 = __builtin_amdgcn_mfma_f32_32x32x16_bf16(v00, p0.v, oa0, 0, 0, 0);
    oa0 = __builtin_amdgcn_mfma_f32_32x32x16_bf16(v01, p1.v, oa0, 0, 0, 0);
    oa1 = __builtin_amdgcn_mfma_f32_32x32x16_bf16(v10, p0.v, oa1, 0, 0, 0);
    oa1 = __builtin_amdgcn_mfma_f32_32x32x16_bf16(v11, p1.v, oa1, 0, 0, 0);
    __builtin_amdgcn_s_setprio(0);
  }

  // ---- combine parity partials ----
  if (parity) {
    float* cp = &cls[ts][lq][0];
#pragma unroll
    for (int t4 = 0; t4 < 4; ++t4) {
      const int d0 = 8 * t4 + 4 * hi;
      f32x4 a = {oa0[4 * t4], oa0[4 * t4 + 1], oa0[4 * t4 + 2], oa0[4 * t4 + 3]};
      f32x4 b = {oa1[4 * t4], oa1[4 * t4 + 1], oa1[4 * t4 + 2], oa1[4 * t4 + 3]};
      *(f32x4*)(cp + d0) = a;
      *(f32x4*)(cp + 32 + d0) = b;
    }
    if (!hi) { mls[ts][lq][0] = mrun; mls[ts][lq][1] = lrun; }
  }
  __syncthreads();
  if (!parity) {
    const float m2 = mls[ts][lq][0], l2 = mls[ts][lq][1];
    const float ms = fmaxf(mrun, m2);
    float b1 = exp2f(mrun - ms), b2 = exp2f(m2 - ms);
    const float linv = 1.0f / (b1 * lrun + b2 * l2);
    b1 *= linv; b2 *= linv;
    const float* cp = &cls[ts][lq][0];
    f32x4 q0[4], q1[4];
#pragma unroll
    for (int t4 = 0; t4 < 4; ++t4) {
      const int d0 = 8 * t4 + 4 * hi;
      q0[t4] = *(const f32x4*)(cp + d0);
      q1[t4] = *(const f32x4*)(cp + 32 + d0);
    }
#pragma unroll
    for (int t4 = 0; t4 < 4; ++t4)
#pragma unroll
      for (int j = 0; j < 4; ++j) {
        oa0[4 * t4 + j] = b1 * oa0[4 * t4 + j] + b2 * q0[t4][j];
        oa1[4 * t4 + j] = b1 * oa1[4 * t4 + j] + b2 * q1[t4][j];
      }
    asm volatile("" ::: "memory");
    // transpose to [q][d] bf16 in the same LDS slot, then coalesced store
    bf16* ol = (bf16*)&cls[ts][0][0];  // [32][80]
#pragma unroll
    for (int t4 = 0; t4 < 4; ++t4) {
      const int d0 = 8 * t4 + 4 * hi;
      *(unsigned int*)(ol + lq * 80 + d0)          = packbf(oa0[4 * t4], oa0[4 * t4 + 1]);
      *(unsigned int*)(ol + lq * 80 + d0 + 2)      = packbf(oa0[4 * t4 + 2], oa0[4 * t4 + 3]);
      *(unsigned int*)(ol + lq * 80 + 32 + d0)     = packbf(oa1[4 * t4], oa1[4 * t4 + 1]);
      *(unsigned int*)(ol + lq * 80 + 32 + d0 + 2) = packbf(oa1[4 * t4 + 2], oa1[4 * t4 + 3]);
    }
    const int b = bh >> 3, h = bh & 7;
#pragma unroll
    for (int ps = 0; ps < 4; ++ps) {
      const int flat = ps * 1024 + lane * 16;
      const int qr = flat >> 7, off = flat & 127;
      bf16x8_t vv = *(const bf16x8_t*)((const char*)ol + qr * 160 + off);
      *(bf16x8_t*)(O + ((size_t)(b * SEQ + qw + qr)) * DIM + h * 64 + off / 2) = vv;
    }
  }
}

// ---------------- host launcher ----------------
extern "C" void kernel_launch(void* const* d_in, const int* in_sizes, int n_in,
                              void* d_out, int out_size, void* d_ws, size_t ws_size,
                              hipStream_t stream) {
  const float* x   = (const float*)d_in[0];
  const float* n1g = (const float*)d_in[1];
  const float* n1b = (const float*)d_in[2];
  const float* wq  = (const float*)d_in[3];
  const float* wk  = (const float*)d_in[4];
  const float* wv  = (const float*)d_in[5];
  const float* wo  = (const float*)d_in[6];
  const float* n2g = (const float*)d_in[7];
  const float* n2b = (const float*)d_in[8];
  const float* w1  = (const float*)d_in[9];
  const float* b1  = (const float*)d_in[10];
  const float* ffg = (const float*)d_in[11];
  const float* ffb = (const float*)d_in[12];
  const float* sww = (const float*)d_in[13];
  const float* swb = (const float*)d_in[14];
  const float* w2  = (const float*)d_in[15];
  const float* b2  = (const float*)d_in[16];
  float* out = (float*)d_out;

  char* ws = (char*)d_ws;
  float* x1 = (float*)(ws + 0);            // 16 MiB
  float* x2 = (float*)(ws + 16777216);     // 16 MiB
  bf16* hbuf   = (bf16*)(ws + 33554432);   // 8 MiB
  bf16* qbuf   = (bf16*)(ws + 41943040);   // 8 MiB (q, later g)
  bf16* kbuf   = (bf16*)(ws + 50331648);   // 8 MiB
  bf16* vtbuf  = (bf16*)(ws + 58720256);   // 8 MiB (V^T)
  bf16* obuf   = (bf16*)(ws + 67108864);   // 8 MiB
  bf16* wbase  = (bf16*)(ws + 75497472);   // 4 MiB contiguous bf16 weights
  bf16* wqkv_b = wbase;                    // [1536][512]
  bf16* wo_b   = wbase + 786432;
  bf16* w1_b   = wbase + 1048576;
  bf16* sw_b16 = wbase + 1310720;          // [1024][512]
  bf16* w2_b   = wbase + 1835008;

  cvt_all_k<<<2048, 256, 0, stream>>>(wq, wk, wv, wo, w1, sww, w2, wbase);

  rmsnorm_k<true><<<ROWS / 2, 256, 0, stream>>>(x, n1g, n1b, x1, hbuf);

  gemm_bt_k<MODE_QKV><<<dim3(64, 24), 256, 0, stream>>>(
      hbuf, wqkv_b, nullptr, nullptr, nullptr, nullptr, qbuf, kbuf, vtbuf);

  attn_k<<<512, 512, 0, stream>>>(qbuf, kbuf, vtbuf, obuf);

  gemm_bt_k<MODE_RES><<<dim3(64, 8), 256, 0, stream>>>(
      obuf, wo_b, nullptr, x1, x2, nullptr, nullptr, nullptr, nullptr);

  rmsnorm_k<false><<<ROWS / 2, 256, 0, stream>>>(x2, n2g, n2b, nullptr, hbuf);

  gemm_bt_k<MODE_BIAS><<<dim3(64, 8), 256, 0, stream>>>(
      hbuf, w1_b, b1, nullptr, x1, nullptr, nullptr, nullptr, nullptr);

  rmsnorm_k<false><<<ROWS / 2, 256, 0, stream>>>(x1, ffg, ffb, nullptr, hbuf);

  gemm_bt_k<MODE_SWIGLU2><<<dim3(64, 8), 256, 0, stream>>>(
      hbuf, sw_b16, swb, nullptr, nullptr, qbuf, nullptr, nullptr, nullptr);

  gemm_bt_k<MODE_RESBIAS><<<dim3(64, 8), 256, 0, stream>>>(
      qbuf, w2_b, b2, x2, out, nullptr, nullptr, nullptr, nullptr);
}

// Round 5
// 190.383 us; speedup vs baseline: 2.0008x; 1.1013x over previous
//
#include <hip/hip_runtime.h>
#include <hip/hip_bf16.h>
#include <cstdint>
#include <cstddef>

typedef __bf16 bf16;
typedef __bf16 bf16x4_t __attribute__((ext_vector_type(4)));
typedef __bf16 bf16x8_t __attribute__((ext_vector_type(8)));
typedef float f32x4 __attribute__((ext_vector_type(4)));
typedef float f32x16 __attribute__((ext_vector_type(16)));

#define DEV_INLINE __device__ __forceinline__

constexpr int SEQ = 2048, DIM = 512, HEADS = 8, DH = 64;
constexpr int ROWS = 4 * SEQ;                     // 8192
constexpr float EPSF = 1.1920928955078125e-07f;   // np.finfo(float32).eps
constexpr float RSQRT_DIM = 0.04419417382415922f; // 512^-0.5
constexpr float LOG2E = 1.44269504088896f;

// ---------------- global->LDS direct (16B per lane) ----------------
DEV_INLINE void load_lds16(const void* g, void* l) {
  __builtin_amdgcn_global_load_lds(
      (const __attribute__((address_space(1))) void*)g,
      (__attribute__((address_space(3))) void*)l,
      16, 0, 0);
}

DEV_INLINE unsigned int packbf(float a, float b) {
  union { unsigned int u; bf16 h[2]; } z;
  z.h[0] = (bf16)a;
  z.h[1] = (bf16)b;
  return z.u;
}

// ---------------- fused fp32 -> bf16 weight convert (1 launch) ----------
__global__ __launch_bounds__(256) void cvt_all_k(
    const float* __restrict__ wq, const float* __restrict__ wk,
    const float* __restrict__ wv, const float* __restrict__ wo,
    const float* __restrict__ w1, const float* __restrict__ sww,
    const float* __restrict__ w2, bf16* __restrict__ dst) {
  const int i = blockIdx.x * 256 + threadIdx.x;  // 0..524287
  const float* src;
  int local;
  if (i < 196608)      { src = (i < 65536) ? wq : (i < 131072) ? wk : wv; local = i & 65535; }
  else if (i < 262144) { src = wo;  local = i - 196608; }
  else if (i < 327680) { src = w1;  local = i - 262144; }
  else if (i < 458752) { src = sww; local = i - 327680; }
  else                 { src = w2;  local = i - 458752; }
  float4 f = reinterpret_cast<const float4*>(src)[local];
  bf16x4_t o;
  o[0] = (bf16)f.x; o[1] = (bf16)f.y; o[2] = (bf16)f.z; o[3] = (bf16)f.w;
  reinterpret_cast<bf16x4_t*>(dst)[i] = o;
}

// ---------------- RMSNorm (float4 vectorized; 2 rows per block) ----------
template <bool ADDPOS>
__global__ __launch_bounds__(256) void rmsnorm_k(const float* __restrict__ in,
                                                 const float* __restrict__ gain,
                                                 const float* __restrict__ bias,
                                                 float* __restrict__ outF,
                                                 bf16* __restrict__ outB) {
  const int sub = threadIdx.x >> 7;
  const int row = blockIdx.x * 2 + sub;
  const int t = threadIdx.x & 127;
  const float* rp = in + (size_t)row * DIM;
  float4 v = reinterpret_cast<const float4*>(rp)[t];
  if constexpr (ADDPOS) {
    const int s = row & (SEQ - 1);
    const float e0 = (float)(4 * t) * (1.0f / (float)DIM);
    const float e1 = (float)(4 * t + 2) * (1.0f / (float)DIM);
    const float d0 = 1.0f / (powf(10000.0f, e0) + EPSF);
    const float d1 = 1.0f / (powf(10000.0f, e1) + EPSF);
    const float a0 = (float)s * d0, a1 = (float)s * d1;
    v.x += sinf(a0); v.y += cosf(a0);
    v.z += sinf(a1); v.w += cosf(a1);
  }
  float ss = v.x * v.x + v.y * v.y + v.z * v.z + v.w * v.w;
#pragma unroll
  for (int off = 32; off > 0; off >>= 1) ss += __shfl_down(ss, off, 64);
  __shared__ float red[4];
  const int wv = threadIdx.x >> 6;
  if ((threadIdx.x & 63) == 0) red[wv] = ss;
  __syncthreads();
  const float total = red[sub * 2] + red[sub * 2 + 1];
  const float scale = sqrtf(total) * RSQRT_DIM;
  const float inv = 1.0f / (scale + EPSF);
  if constexpr (ADDPOS)
    reinterpret_cast<float4*>(outF + (size_t)row * DIM)[t] = v;
  const float4 g = reinterpret_cast<const float4*>(gain)[t];
  const float4 bb = reinterpret_cast<const float4*>(bias)[t];
  bf16x4_t o;
  o[0] = (bf16)(v.x * inv * g.x + bb.x);
  o[1] = (bf16)(v.y * inv * g.y + bb.y);
  o[2] = (bf16)(v.z * inv * g.z + bb.z);
  o[3] = (bf16)(v.w * inv * g.w + bb.w);
  reinterpret_cast<bf16x4_t*>(outB + (size_t)row * DIM)[t] = o;
}

// ---------------- GEMM: C[M,N] = A[M,512] @ Bt[N,512]^T ----------------
// BM=128, BN=64, BK=32; 256 thr (2x2 waves, 64x32/wave). 3-stage pipeline.
// MODE_QKV: LDS-staged vectorized epilogue (token-major Q/K, transposed V).
enum { MODE_QKV = 0, MODE_RES = 1, MODE_BIAS = 2, MODE_SWIGLU2 = 3, MODE_RESBIAS = 4 };

template <int MODE>
__global__ __launch_bounds__(256) void gemm_bt_k(
    const bf16* __restrict__ A, const bf16* __restrict__ Bt,
    const float* __restrict__ bias, const float* __restrict__ res,
    float* __restrict__ outF, bf16* __restrict__ outB,
    bf16* __restrict__ oq, bf16* __restrict__ okk, bf16* __restrict__ ovT) {
  constexpr int BELEMS = (MODE == MODE_SWIGLU2) ? 4096 : 2048;
  __shared__ __align__(16) bf16 sA[3][128 * 32];
  __shared__ __align__(16) bf16 sB[3][BELEMS];
  const int tid = threadIdx.x;
  const int wave = tid >> 6, lane = tid & 63;
  const int m0 = blockIdx.x * 128, n0 = blockIdx.y * 64;
  const int wm = wave >> 1, wn = wave & 1;
  const int lr = lane & 15, lk = (lane >> 4) * 8;

  const f32x4 fzero = {0.f, 0.f, 0.f, 0.f};
  f32x4 acc[4][2], acc2[4][2];
#pragma unroll
  for (int i = 0; i < 4; ++i)
#pragma unroll
    for (int j = 0; j < 2; ++j) { acc[i][j] = fzero; acc2[i][j] = fzero; }

  const int off0 = wave * 1024 + lane * 16;
  const int rowS = off0 >> 6, colb = off0 & 63;

  auto stage = [&](int buf, int kt) {
    const int k0 = kt * 32;
    load_lds16((const char*)A + ((size_t)(m0 + rowS) * 512 + k0) * 2 + colb,
               (char*)&sA[buf][0] + off0);
    load_lds16((const char*)A + ((size_t)(m0 + 64 + rowS) * 512 + k0) * 2 + colb,
               (char*)&sA[buf][0] + 4096 + off0);
    load_lds16((const char*)Bt + ((size_t)(n0 + rowS) * 512 + k0) * 2 + colb,
               (char*)&sB[buf][0] + off0);
    if constexpr (MODE == MODE_SWIGLU2)
      load_lds16((const char*)Bt + ((size_t)(512 + n0 + rowS) * 512 + k0) * 2 + colb,
                 (char*)&sB[buf][0] + 4096 + off0);
  };

  stage(0, 0);
  stage(1, 1);
  if constexpr (MODE == MODE_SWIGLU2)
    asm volatile("s_waitcnt vmcnt(4)\ns_barrier" ::: "memory");
  else
    asm volatile("s_waitcnt vmcnt(3)\ns_barrier" ::: "memory");

#pragma unroll
  for (int kt = 0; kt < 16; ++kt) {
    const int cur = kt % 3;
    if (kt + 2 < 16) stage((kt + 2) % 3, kt + 2);
    bf16x8_t af[4], bfr[2], bfr2[2];
#pragma unroll
    for (int mf = 0; mf < 4; ++mf)
      af[mf] = *(const bf16x8_t*)(&sA[cur][0] + (wm * 64 + mf * 16 + lr) * 32 + lk);
#pragma unroll
    for (int nf = 0; nf < 2; ++nf)
      bfr[nf] = *(const bf16x8_t*)(&sB[cur][0] + (wn * 32 + nf * 16 + lr) * 32 + lk);
    if constexpr (MODE == MODE_SWIGLU2) {
#pragma unroll
      for (int nf = 0; nf < 2; ++nf)
        bfr2[nf] = *(const bf16x8_t*)(&sB[cur][0] + 2048 + (wn * 32 + nf * 16 + lr) * 32 + lk);
    }
    asm volatile("s_waitcnt lgkmcnt(0)" ::: "memory");
#pragma unroll
    for (int mf = 0; mf < 4; ++mf)
#pragma unroll
      for (int nf = 0; nf < 2; ++nf) {
        acc[mf][nf] = __builtin_amdgcn_mfma_f32_16x16x32_bf16(af[mf], bfr[nf],
                                                              acc[mf][nf], 0, 0, 0);
        if constexpr (MODE == MODE_SWIGLU2)
          acc2[mf][nf] = __builtin_amdgcn_mfma_f32_16x16x32_bf16(af[mf], bfr2[nf],
                                                                 acc2[mf][nf], 0, 0, 0);
      }
    if (kt < 14) {
      if constexpr (MODE == MODE_SWIGLU2)
        asm volatile("s_waitcnt vmcnt(4)\ns_barrier" ::: "memory");
      else
        asm volatile("s_waitcnt vmcnt(3)\ns_barrier" ::: "memory");
    } else if (kt < 15) {
      asm volatile("s_waitcnt vmcnt(0)\ns_barrier" ::: "memory");
    }
  }

  if constexpr (MODE == MODE_QKV) {
    // ---- LDS-staged vectorized epilogue ----
    // Each block covers one head's 64 channels: which/h uniform per block.
    const int which = n0 >> 9;          // 0=q 1=k 2=v
    const int h = (n0 >> 6) & 7;
    const int b = m0 >> 11;             // 128-row blocks never cross batch
    const int s0tok = m0 & 2047;
    bf16* st = &sA[0][0];               // reuse staging (>=18KB free)
    const int rb = wm * 64 + (lane >> 4) * 4;
    const int cb = wn * 32 + lr;
    __syncthreads();                    // all waves done reading sA/sB
    if (which < 2) {
      // token-major [128][72]
#pragma unroll
      for (int mf = 0; mf < 4; ++mf)
#pragma unroll
        for (int nf = 0; nf < 2; ++nf)
#pragma unroll
          for (int rg = 0; rg < 4; ++rg) {
            float v = acc[mf][nf][rg];
            if (which == 0) v *= RSQRT_DIM * LOG2E;
            st[(rb + mf * 16 + rg) * 72 + cb + nf * 16] = (bf16)v;
          }
      __syncthreads();
      bf16* dst = which == 0 ? oq : okk;
#pragma unroll
      for (int j = 0; j < 4; ++j) {
        const int flat = j * 4096 + tid * 16;       // bytes in 128x128B
        const int row = flat >> 7, offb = flat & 127;
        bf16x8_t vv = *(const bf16x8_t*)(st + row * 72 + offb / 2);
        const size_t addr =
            ((size_t)((b * HEADS + h) * SEQ + s0tok + row)) * DH + offb / 2;
        *(bf16x8_t*)(dst + addr) = vv;
      }
    } else {
      // transposed [64][136] -> V^T
#pragma unroll
      for (int mf = 0; mf < 4; ++mf)
#pragma unroll
        for (int nf = 0; nf < 2; ++nf)
#pragma unroll
          for (int rg = 0; rg < 4; ++rg)
            st[(cb + nf * 16) * 136 + rb + mf * 16 + rg] = (bf16)acc[mf][nf][rg];
      __syncthreads();
#pragma unroll
      for (int j = 0; j < 4; ++j) {
        const int flat = j * 4096 + tid * 16;       // bytes in 64x256B
        const int row = flat >> 8, offb = flat & 255;
        bf16x8_t vv = *(const bf16x8_t*)(st + row * 136 + offb / 2);
        const size_t addr =
            ((size_t)((b * HEADS + h) * DH + row)) * SEQ + s0tok + offb / 2;
        *(bf16x8_t*)(ovT + addr) = vv;
      }
    }
    return;
  }

  const int rbase = m0 + wm * 64 + (lane >> 4) * 4;
  const int cbase = n0 + wn * 32 + lr;
#pragma unroll
  for (int mf = 0; mf < 4; ++mf) {
#pragma unroll
    for (int nf = 0; nf < 2; ++nf) {
      const int c = cbase + nf * 16;
#pragma unroll
      for (int rg = 0; rg < 4; ++rg) {
        const int r = rbase + mf * 16 + rg;
        float v = acc[mf][nf][rg];
        if constexpr (MODE == MODE_RES) {
          const size_t idx = (size_t)r * 512 + c;
          outF[idx] = res[idx] + v;
        } else if constexpr (MODE == MODE_BIAS) {
          const size_t idx = (size_t)r * 512 + c;
          outF[idx] = v + bias[c];
        } else if constexpr (MODE == MODE_SWIGLU2) {
          const size_t idx = (size_t)r * 512 + c;
          const float u1 = v + bias[c];
          const float u2 = acc2[mf][nf][rg] + bias[512 + c];
          const float sig = 1.0f / (1.0f + __expf(-u1));
          outB[idx] = (bf16)(u1 * sig + u2);
        } else {
          const size_t idx = (size_t)r * 512 + c;
          outF[idx] = res[idx] + v + bias[c];
        }
      }
    }
  }
}

// ---------------- causal flash attention: KVBLK=64 + split-K parity -------
// 512 blocks x 512 thr (8 waves). Block -> (bh, 4 q-tiles {j,63-j,31-j,32+j})
// -> constant 66 k-iters/block (perfect balance). Each 32-row q-tile has 2
// waves on even/odd 64-wide k-tiles, independent online softmax (exp2 domain,
// q pre-scaled by log2e/sqrt(D)), T13 defer-rescale, LDS combine at end.
// VGPR capped 128 -> 2 blocks/CU -> 4 waves/SIMD.
__global__ __launch_bounds__(512, 4) void attn_k(const bf16* __restrict__ Q,
                                                 const bf16* __restrict__ K,
                                                 const bf16* __restrict__ VT,
                                                 bf16* __restrict__ O) {
  const int tid = threadIdx.x;
  const int wave = tid >> 6, lane = tid & 63;
  const int lq = lane & 31, hi = lane >> 5;

  const int wg = blockIdx.x;                 // 0..511
  const int xcd = wg & 7;
  const int bh = xcd * 4 + ((wg >> 3) & 3);
  const int j = wg >> 5;                     // 0..15 block-slot
  const int ts = wave >> 1, parity = wave & 1;
  const int t = (ts == 0) ? j : (ts == 1) ? (63 - j) : (ts == 2) ? (31 - j) : (32 + j);
  const int qw = t * 32;
  const int nkt = t / 2 + 1;                 // 64-wide k-tiles

  const bf16* Qb = Q + (size_t)bh * SEQ * DH;
  const bf16* Kb = K + (size_t)bh * SEQ * DH;
  const bf16* Vb = VT + (size_t)bh * DH * SEQ;

  __shared__ __align__(16) float cls[4][32][72];
  __shared__ float mls[4][32][2];

  bf16x8_t qf[4];
  {
    const bf16* qp = Qb + (size_t)(qw + lq) * DH + 8 * hi;
    qf[0] = *(const bf16x8_t*)(qp);
    qf[1] = *(const bf16x8_t*)(qp + 16);
    qf[2] = *(const bf16x8_t*)(qp + 32);
    qf[3] = *(const bf16x8_t*)(qp + 48);
  }

  f32x16 oa0, oa1;
#pragma unroll
  for (int r = 0; r < 16; ++r) { oa0[r] = 0.f; oa1[r] = 0.f; }
  float mrun = -3.0e38f, lrun = 0.f;

  for (int kt = parity; kt < nkt; kt += 2) {
    // ---- K fragments: two 32-row k-blocks ----
    const bf16* kp0 = Kb + (size_t)(kt * 64 + lq) * DH + 8 * hi;
    const bf16* kp1 = kp0 + 32 * DH;
    f32x16 s0, s1;
#pragma unroll
    for (int r = 0; r < 16; ++r) { s0[r] = 0.f; s1[r] = 0.f; }
    __builtin_amdgcn_s_setprio(1);
#pragma unroll
    for (int s = 0; s < 4; ++s) {
      s0 = __builtin_amdgcn_mfma_f32_32x32x16_bf16(*(const bf16x8_t*)(kp0 + 16 * s),
                                                   qf[s], s0, 0, 0, 0);
      s1 = __builtin_amdgcn_mfma_f32_32x32x16_bf16(*(const bf16x8_t*)(kp1 + 16 * s),
                                                   qf[s], s1, 0, 0, 0);
    }
    __builtin_amdgcn_s_setprio(0);

    // ---- V loads (consumed after softmax; latency hidden under it) ----
    const bf16* vp0 = Vb + (size_t)lq * SEQ + kt * 64 + 8 * hi;
    const bf16* vp1 = vp0 + 32 * SEQ;
    bf16x8_t v00 = *(const bf16x8_t*)(vp0);
    bf16x8_t v01 = *(const bf16x8_t*)(vp0 + 16);
    bf16x8_t v02 = *(const bf16x8_t*)(vp0 + 32);
    bf16x8_t v03 = *(const bf16x8_t*)(vp0 + 48);
    bf16x8_t v10 = *(const bf16x8_t*)(vp1);
    bf16x8_t v11 = *(const bf16x8_t*)(vp1 + 16);
    bf16x8_t v12 = *(const bf16x8_t*)(vp1 + 32);
    bf16x8_t v13 = *(const bf16x8_t*)(vp1 + 48);

    // ---- causal mask (only the final k-tile of this q-tile) ----
    if (kt == nkt - 1) {
      const int qg = qw + lq;
#pragma unroll
      for (int r = 0; r < 16; ++r) {
        const int kl = kt * 64 + (r & 3) + 8 * (r >> 2) + 4 * hi;
        if (kl > qg) s0[r] = -3.0e38f;
        if (kl + 32 > qg) s1[r] = -3.0e38f;
      }
    }

    // ---- online softmax (exp2 domain), defer-rescale (T13) ----
    float mt = -3.0e38f;
#pragma unroll
    for (int r = 0; r < 16; ++r) mt = fmaxf(mt, fmaxf(s0[r], s1[r]));
    mt = fmaxf(mt, __shfl_xor(mt, 32));
    float mbase = mrun;
    if (!__all(mt <= mrun + 8.0f)) {
      mbase = fmaxf(mrun, mt);
      const float alpha = exp2f(mrun - mbase);
      mrun = mbase;
      lrun *= alpha;
#pragma unroll
      for (int r = 0; r < 16; ++r) { oa0[r] *= alpha; oa1[r] *= alpha; }
    }
    float sum = 0.f;
#pragma unroll
    for (int r = 0; r < 16; ++r) {
      const float a = exp2f(s0[r] - mbase); s0[r] = a; sum += a;
      const float bb = exp2f(s1[r] - mbase); s1[r] = bb; sum += bb;
    }
    sum += __shfl_xor(sum, 32);
    lrun += sum;

    // ---- pack P -> PV B-fragments ----
    unsigned int wa0[4], wb0[4], wa1[4], wb1[4];
#pragma unroll
    for (int t4 = 0; t4 < 4; ++t4) {
      wa0[t4] = packbf(s0[4 * t4], s0[4 * t4 + 1]);
      wb0[t4] = packbf(s0[4 * t4 + 2], s0[4 * t4 + 3]);
      wa1[t4] = packbf(s1[4 * t4], s1[4 * t4 + 1]);
      wb1[t4] = packbf(s1[4 * t4 + 2], s1[4 * t4 + 3]);
    }
    unsigned int xa0[4], xb0[4], xa1[4], xb1[4];
#pragma unroll
    for (int t4 = 0; t4 < 4; ++t4) {
      xa0[t4] = __shfl_xor((int)wa0[t4], 32);
      xb0[t4] = __shfl_xor((int)wb0[t4], 32);
      xa1[t4] = __shfl_xor((int)wa1[t4], 32);
      xb1[t4] = __shfl_xor((int)wb1[t4], 32);
    }
    union U8 { unsigned int u[4]; bf16x8_t v; };
    U8 p00, p01, p10, p11;
    p00.u[0] = hi ? xa0[1] : wa0[0]; p00.u[1] = hi ? xb0[1] : wb0[0];
    p00.u[2] = hi ? wa0[1] : xa0[0]; p00.u[3] = hi ? wb0[1] : xb0[0];
    p01.u[0] = hi ? xa0[3] : wa0[2]; p01.u[1] = hi ? xb0[3] : wb0[2];
    p01.u[2] = hi ? wa0[3] : xa0[2]; p01.u[3] = hi ? wb0[3] : xb0[2];
    p10.u[0] = hi ? xa1[1] : wa1[0]; p10.u[1] = hi ? xb1[1] : wb1[0];
    p10.u[2] = hi ? wa1[1] : xa1[0]; p10.u[3] = hi ? wb1[1] : xb1[0];
    p11.u[0] = hi ? xa1[3] : wa1[2]; p11.u[1] = hi ? xb1[3] : wb1[2];
    p11.u[2] = hi ? wa1[3] : xa1[2]; p11.u[3] = hi ? wb1[3] : xb1[2];

    // ---- O^T += V^T . P ----
    __builtin_amdgcn_s_setprio(1);
    oa0 = __builtin_amdgcn_mfma_f32_32x32x16_bf16(v00, p00.v, oa0, 0, 0, 0);
    oa0 = __builtin_amdgcn_mfma_f32_32x32x16_bf16(v01, p01.v, oa0, 0, 0, 0);
    oa0 = __builtin_amdgcn_mfma_f32_32x32x16_bf16(v02, p10.v, oa0, 0, 0, 0);
    oa0 = __builtin_amdgcn_mfma_f32_32x32x16_bf16(v03, p11.v, oa0, 0, 0, 0);
    oa1 = __builtin_amdgcn_mfma_f32_32x32x16_bf16(v10, p00.v, oa1, 0, 0, 0);
    oa1 = __builtin_amdgcn_mfma_f32_32x32x16_bf16(v11, p01.v, oa1, 0, 0, 0);
    oa1 = __builtin_amdgcn_mfma_f32_32x32x16_bf16(v12, p10.v, oa1, 0, 0, 0);
    oa1 = __builtin_amdgcn_mfma_f32_32x32x16_bf16(v13, p11.v, oa1, 0, 0, 0);
    __builtin_amdgcn_s_setprio(0);
  }

  // ---- combine parity partials ----
  if (parity) {
    float* cp = &cls[ts][lq][0];
#pragma unroll
    for (int t4 = 0; t4 < 4; ++t4) {
      const int d0 = 8 * t4 + 4 * hi;
      f32x4 a = {oa0[4 * t4], oa0[4 * t4 + 1], oa0[4 * t4 + 2], oa0[4 * t4 + 3]};
      f32x4 b = {oa1[4 * t4], oa1[4 * t4 + 1], oa1[4 * t4 + 2], oa1[4 * t4 + 3]};
      *(f32x4*)(cp + d0) = a;
      *(f32x4*)(cp + 32 + d0) = b;
    }
    if (!hi) { mls[ts][lq][0] = mrun; mls[ts][lq][1] = lrun; }
  }
  __syncthreads();
  if (!parity) {
    const float m2 = mls[ts][lq][0], l2 = mls[ts][lq][1];
    const float ms = fmaxf(mrun, m2);
    float b1 = exp2f(mrun - ms), b2 = exp2f(m2 - ms);
    const float linv = 1.0f / (b1 * lrun + b2 * l2);
    b1 *= linv; b2 *= linv;
    const float* cp = &cls[ts][lq][0];
    f32x4 q0[4], q1[4];
#pragma unroll
    for (int t4 = 0; t4 < 4; ++t4) {
      const int d0 = 8 * t4 + 4 * hi;
      q0[t4] = *(const f32x4*)(cp + d0);
      q1[t4] = *(const f32x4*)(cp + 32 + d0);
    }
#pragma unroll
    for (int t4 = 0; t4 < 4; ++t4)
#pragma unroll
      for (int jj = 0; jj < 4; ++jj) {
        oa0[4 * t4 + jj] = b1 * oa0[4 * t4 + jj] + b2 * q0[t4][jj];
        oa1[4 * t4 + jj] = b1 * oa1[4 * t4 + jj] + b2 * q1[t4][jj];
      }
    asm volatile("" ::: "memory");
    // transpose to [q][d] bf16 in the same LDS slot, then coalesced store
    bf16* ol = (bf16*)&cls[ts][0][0];  // [32][80]
#pragma unroll
    for (int t4 = 0; t4 < 4; ++t4) {
      const int d0 = 8 * t4 + 4 * hi;
      *(unsigned int*)(ol + lq * 80 + d0)          = packbf(oa0[4 * t4], oa0[4 * t4 + 1]);
      *(unsigned int*)(ol + lq * 80 + d0 + 2)      = packbf(oa0[4 * t4 + 2], oa0[4 * t4 + 3]);
      *(unsigned int*)(ol + lq * 80 + 32 + d0)     = packbf(oa1[4 * t4], oa1[4 * t4 + 1]);
      *(unsigned int*)(ol + lq * 80 + 32 + d0 + 2) = packbf(oa1[4 * t4 + 2], oa1[4 * t4 + 3]);
    }
    const int b = bh >> 3, h = bh & 7;
#pragma unroll
    for (int ps = 0; ps < 4; ++ps) {
      const int flat = ps * 1024 + lane * 16;
      const int qr = flat >> 7, off = flat & 127;
      bf16x8_t vv = *(const bf16x8_t*)((const char*)ol + qr * 160 + off);
      *(bf16x8_t*)(O + ((size_t)(b * SEQ + qw + qr)) * DIM + h * 64 + off / 2) = vv;
    }
  }
}

// ---------------- host launcher ----------------
extern "C" void kernel_launch(void* const* d_in, const int* in_sizes, int n_in,
                              void* d_out, int out_size, void* d_ws, size_t ws_size,
                              hipStream_t stream) {
  const float* x   = (const float*)d_in[0];
  const float* n1g = (const float*)d_in[1];
  const float* n1b = (const float*)d_in[2];
  const float* wq  = (const float*)d_in[3];
  const float* wk  = (const float*)d_in[4];
  const float* wv  = (const float*)d_in[5];
  const float* wo  = (const float*)d_in[6];
  const float* n2g = (const float*)d_in[7];
  const float* n2b = (const float*)d_in[8];
  const float* w1  = (const float*)d_in[9];
  const float* b1  = (const float*)d_in[10];
  const float* ffg = (const float*)d_in[11];
  const float* ffb = (const float*)d_in[12];
  const float* sww = (const float*)d_in[13];
  const float* swb = (const float*)d_in[14];
  const float* w2  = (const float*)d_in[15];
  const float* b2  = (const float*)d_in[16];
  float* out = (float*)d_out;

  char* ws = (char*)d_ws;
  float* x1 = (float*)(ws + 0);            // 16 MiB
  float* x2 = (float*)(ws + 16777216);     // 16 MiB
  bf16* hbuf   = (bf16*)(ws + 33554432);   // 8 MiB
  bf16* qbuf   = (bf16*)(ws + 41943040);   // 8 MiB (q, later g)
  bf16* kbuf   = (bf16*)(ws + 50331648);   // 8 MiB
  bf16* vtbuf  = (bf16*)(ws + 58720256);   // 8 MiB (V^T)
  bf16* obuf   = (bf16*)(ws + 67108864);   // 8 MiB
  bf16* wbase  = (bf16*)(ws + 75497472);   // 4 MiB contiguous bf16 weights
  bf16* wqkv_b = wbase;                    // [1536][512]
  bf16* wo_b   = wbase + 786432;
  bf16* w1_b   = wbase + 1048576;
  bf16* sw_b16 = wbase + 1310720;          // [1024][512]
  bf16* w2_b   = wbase + 1835008;

  cvt_all_k<<<2048, 256, 0, stream>>>(wq, wk, wv, wo, w1, sww, w2, wbase);

  rmsnorm_k<true><<<ROWS / 2, 256, 0, stream>>>(x, n1g, n1b, x1, hbuf);

  gemm_bt_k<MODE_QKV><<<dim3(64, 24), 256, 0, stream>>>(
      hbuf, wqkv_b, nullptr, nullptr, nullptr, nullptr, qbuf, kbuf, vtbuf);

  attn_k<<<512, 512, 0, stream>>>(qbuf, kbuf, vtbuf, obuf);

  gemm_bt_k<MODE_RES><<<dim3(64, 8), 256, 0, stream>>>(
      obuf, wo_b, nullptr, x1, x2, nullptr, nullptr, nullptr, nullptr);

  rmsnorm_k<false><<<ROWS / 2, 256, 0, stream>>>(x2, n2g, n2b, nullptr, hbuf);

  gemm_bt_k<MODE_BIAS><<<dim3(64, 8), 256, 0, stream>>>(
      hbuf, w1_b, b1, nullptr, x1, nullptr, nullptr, nullptr, nullptr);

  rmsnorm_k<false><<<ROWS / 2, 256, 0, stream>>>(x1, ffg, ffb, nullptr, hbuf);

  gemm_bt_k<MODE_SWIGLU2><<<dim3(64, 8), 256, 0, stream>>>(
      hbuf, sw_b16, swb, nullptr, nullptr, qbuf, nullptr, nullptr, nullptr);

  gemm_bt_k<MODE_RESBIAS><<<dim3(64, 8), 256, 0, stream>>>(
      qbuf, w2_b, b2, x2, out, nullptr, nullptr, nullptr, nullptr);
}

// Round 6
// 187.500 us; speedup vs baseline: 2.0316x; 1.0154x over previous
//
#include <hip/hip_runtime.h>
#include <hip/hip_bf16.h>
#include <cstdint>
#include <cstddef>

typedef __bf16 bf16;
typedef __bf16 bf16x4_t __attribute__((ext_vector_type(4)));
typedef __bf16 bf16x8_t __attribute__((ext_vector_type(8)));
typedef float f32x4 __attribute__((ext_vector_type(4)));
typedef float f32x16 __attribute__((ext_vector_type(16)));

#define DEV_INLINE __device__ __forceinline__

constexpr int SEQ = 2048, DIM = 512, HEADS = 8, DH = 64;
constexpr int ROWS = 4 * SEQ;                     // 8192
constexpr float EPSF = 1.1920928955078125e-07f;   // np.finfo(float32).eps
constexpr float RSQRT_DIM = 0.04419417382415922f; // 512^-0.5
constexpr float LOG2E = 1.44269504088896f;

// ---------------- global->LDS direct (16B per lane) ----------------
DEV_INLINE void load_lds16(const void* g, void* l) {
  __builtin_amdgcn_global_load_lds(
      (const __attribute__((address_space(1))) void*)g,
      (__attribute__((address_space(3))) void*)l,
      16, 0, 0);
}

DEV_INLINE unsigned int packbf(float a, float b) {
  union { unsigned int u; bf16 h[2]; } z;
  z.h[0] = (bf16)a;
  z.h[1] = (bf16)b;
  return z.u;
}

// one v_permlane32_swap_b32: a' = [a_lo, b_lo-as-hi], b' = [a_hi-as-lo, b_hi]
DEV_INLINE void permswap(unsigned int& a, unsigned int& b) {
  asm volatile("v_permlane32_swap_b32 %0, %1" : "+v"(a), "+v"(b));
}

// ---------------- fused fp32 -> bf16 weight convert (1 launch) ----------
__global__ __launch_bounds__(256) void cvt_all_k(
    const float* __restrict__ wq, const float* __restrict__ wk,
    const float* __restrict__ wv, const float* __restrict__ wo,
    const float* __restrict__ w1, const float* __restrict__ sww,
    const float* __restrict__ w2, bf16* __restrict__ dst) {
  const int i = blockIdx.x * 256 + threadIdx.x;  // 0..524287
  const float* src;
  int local;
  if (i < 196608)      { src = (i < 65536) ? wq : (i < 131072) ? wk : wv; local = i & 65535; }
  else if (i < 262144) { src = wo;  local = i - 196608; }
  else if (i < 327680) { src = w1;  local = i - 262144; }
  else if (i < 458752) { src = sww; local = i - 327680; }
  else                 { src = w2;  local = i - 458752; }
  float4 f = reinterpret_cast<const float4*>(src)[local];
  bf16x4_t o;
  o[0] = (bf16)f.x; o[1] = (bf16)f.y; o[2] = (bf16)f.z; o[3] = (bf16)f.w;
  reinterpret_cast<bf16x4_t*>(dst)[i] = o;
}

// ---------------- RMSNorm (float4 vectorized; 2 rows per block) ----------
template <bool ADDPOS>
__global__ __launch_bounds__(256) void rmsnorm_k(const float* __restrict__ in,
                                                 const float* __restrict__ gain,
                                                 const float* __restrict__ bias,
                                                 float* __restrict__ outF,
                                                 bf16* __restrict__ outB) {
  const int sub = threadIdx.x >> 7;
  const int row = blockIdx.x * 2 + sub;
  const int t = threadIdx.x & 127;
  const float* rp = in + (size_t)row * DIM;
  float4 v = reinterpret_cast<const float4*>(rp)[t];
  if constexpr (ADDPOS) {
    const int s = row & (SEQ - 1);
    const float e0 = (float)(4 * t) * (1.0f / (float)DIM);
    const float e1 = (float)(4 * t + 2) * (1.0f / (float)DIM);
    const float d0 = 1.0f / (powf(10000.0f, e0) + EPSF);
    const float d1 = 1.0f / (powf(10000.0f, e1) + EPSF);
    const float a0 = (float)s * d0, a1 = (float)s * d1;
    v.x += sinf(a0); v.y += cosf(a0);
    v.z += sinf(a1); v.w += cosf(a1);
  }
  float ss = v.x * v.x + v.y * v.y + v.z * v.z + v.w * v.w;
#pragma unroll
  for (int off = 32; off > 0; off >>= 1) ss += __shfl_down(ss, off, 64);
  __shared__ float red[4];
  const int wv = threadIdx.x >> 6;
  if ((threadIdx.x & 63) == 0) red[wv] = ss;
  __syncthreads();
  const float total = red[sub * 2] + red[sub * 2 + 1];
  const float scale = sqrtf(total) * RSQRT_DIM;
  const float inv = 1.0f / (scale + EPSF);
  if constexpr (ADDPOS)
    reinterpret_cast<float4*>(outF + (size_t)row * DIM)[t] = v;
  const float4 g = reinterpret_cast<const float4*>(gain)[t];
  const float4 bb = reinterpret_cast<const float4*>(bias)[t];
  bf16x4_t o;
  o[0] = (bf16)(v.x * inv * g.x + bb.x);
  o[1] = (bf16)(v.y * inv * g.y + bb.y);
  o[2] = (bf16)(v.z * inv * g.z + bb.z);
  o[3] = (bf16)(v.w * inv * g.w + bb.w);
  reinterpret_cast<bf16x4_t*>(outB + (size_t)row * DIM)[t] = o;
}

// ---------------- GEMM: C[M,N] = A[M,512] @ Bt[N,512]^T ----------------
enum { MODE_QKV = 0, MODE_RES = 1, MODE_BIAS = 2, MODE_SWIGLU2 = 3, MODE_RESBIAS = 4 };

template <int MODE>
__global__ __launch_bounds__(256) void gemm_bt_k(
    const bf16* __restrict__ A, const bf16* __restrict__ Bt,
    const float* __restrict__ bias, const float* __restrict__ res,
    float* __restrict__ outF, bf16* __restrict__ outB,
    bf16* __restrict__ oq, bf16* __restrict__ okk, bf16* __restrict__ ovT) {
  constexpr int BELEMS = (MODE == MODE_SWIGLU2) ? 4096 : 2048;
  __shared__ __align__(16) bf16 sA[3][128 * 32];
  __shared__ __align__(16) bf16 sB[3][BELEMS];
  const int tid = threadIdx.x;
  const int wave = tid >> 6, lane = tid & 63;
  const int m0 = blockIdx.x * 128, n0 = blockIdx.y * 64;
  const int wm = wave >> 1, wn = wave & 1;
  const int lr = lane & 15, lk = (lane >> 4) * 8;

  const f32x4 fzero = {0.f, 0.f, 0.f, 0.f};
  f32x4 acc[4][2], acc2[4][2];
#pragma unroll
  for (int i = 0; i < 4; ++i)
#pragma unroll
    for (int j = 0; j < 2; ++j) { acc[i][j] = fzero; acc2[i][j] = fzero; }

  const int off0 = wave * 1024 + lane * 16;
  const int rowS = off0 >> 6, colb = off0 & 63;

  auto stage = [&](int buf, int kt) {
    const int k0 = kt * 32;
    load_lds16((const char*)A + ((size_t)(m0 + rowS) * 512 + k0) * 2 + colb,
               (char*)&sA[buf][0] + off0);
    load_lds16((const char*)A + ((size_t)(m0 + 64 + rowS) * 512 + k0) * 2 + colb,
               (char*)&sA[buf][0] + 4096 + off0);
    load_lds16((const char*)Bt + ((size_t)(n0 + rowS) * 512 + k0) * 2 + colb,
               (char*)&sB[buf][0] + off0);
    if constexpr (MODE == MODE_SWIGLU2)
      load_lds16((const char*)Bt + ((size_t)(512 + n0 + rowS) * 512 + k0) * 2 + colb,
                 (char*)&sB[buf][0] + 4096 + off0);
  };

  stage(0, 0);
  stage(1, 1);
  if constexpr (MODE == MODE_SWIGLU2)
    asm volatile("s_waitcnt vmcnt(4)\ns_barrier" ::: "memory");
  else
    asm volatile("s_waitcnt vmcnt(3)\ns_barrier" ::: "memory");

#pragma unroll
  for (int kt = 0; kt < 16; ++kt) {
    const int cur = kt % 3;
    if (kt + 2 < 16) stage((kt + 2) % 3, kt + 2);
    bf16x8_t af[4], bfr[2], bfr2[2];
#pragma unroll
    for (int mf = 0; mf < 4; ++mf)
      af[mf] = *(const bf16x8_t*)(&sA[cur][0] + (wm * 64 + mf * 16 + lr) * 32 + lk);
#pragma unroll
    for (int nf = 0; nf < 2; ++nf)
      bfr[nf] = *(const bf16x8_t*)(&sB[cur][0] + (wn * 32 + nf * 16 + lr) * 32 + lk);
    if constexpr (MODE == MODE_SWIGLU2) {
#pragma unroll
      for (int nf = 0; nf < 2; ++nf)
        bfr2[nf] = *(const bf16x8_t*)(&sB[cur][0] + 2048 + (wn * 32 + nf * 16 + lr) * 32 + lk);
    }
    asm volatile("s_waitcnt lgkmcnt(0)" ::: "memory");
#pragma unroll
    for (int mf = 0; mf < 4; ++mf)
#pragma unroll
      for (int nf = 0; nf < 2; ++nf) {
        acc[mf][nf] = __builtin_amdgcn_mfma_f32_16x16x32_bf16(af[mf], bfr[nf],
                                                              acc[mf][nf], 0, 0, 0);
        if constexpr (MODE == MODE_SWIGLU2)
          acc2[mf][nf] = __builtin_amdgcn_mfma_f32_16x16x32_bf16(af[mf], bfr2[nf],
                                                                 acc2[mf][nf], 0, 0, 0);
      }
    if (kt < 14) {
      if constexpr (MODE == MODE_SWIGLU2)
        asm volatile("s_waitcnt vmcnt(4)\ns_barrier" ::: "memory");
      else
        asm volatile("s_waitcnt vmcnt(3)\ns_barrier" ::: "memory");
    } else if (kt < 15) {
      asm volatile("s_waitcnt vmcnt(0)\ns_barrier" ::: "memory");
    }
  }

  if constexpr (MODE == MODE_QKV) {
    // ---- LDS-staged vectorized epilogue ----
    const int which = n0 >> 9;          // 0=q 1=k 2=v
    const int h = (n0 >> 6) & 7;
    const int b = m0 >> 11;
    const int s0tok = m0 & 2047;
    bf16* st = &sA[0][0];
    const int rb = wm * 64 + (lane >> 4) * 4;
    const int cb = wn * 32 + lr;
    __syncthreads();
    if (which < 2) {
#pragma unroll
      for (int mf = 0; mf < 4; ++mf)
#pragma unroll
        for (int nf = 0; nf < 2; ++nf)
#pragma unroll
          for (int rg = 0; rg < 4; ++rg) {
            float v = acc[mf][nf][rg];
            if (which == 0) v *= RSQRT_DIM * LOG2E;
            st[(rb + mf * 16 + rg) * 72 + cb + nf * 16] = (bf16)v;
          }
      __syncthreads();
      bf16* dst = which == 0 ? oq : okk;
#pragma unroll
      for (int j = 0; j < 4; ++j) {
        const int flat = j * 4096 + tid * 16;
        const int row = flat >> 7, offb = flat & 127;
        bf16x8_t vv = *(const bf16x8_t*)(st + row * 72 + offb / 2);
        const size_t addr =
            ((size_t)((b * HEADS + h) * SEQ + s0tok + row)) * DH + offb / 2;
        *(bf16x8_t*)(dst + addr) = vv;
      }
    } else {
#pragma unroll
      for (int mf = 0; mf < 4; ++mf)
#pragma unroll
        for (int nf = 0; nf < 2; ++nf)
#pragma unroll
          for (int rg = 0; rg < 4; ++rg)
            st[(cb + nf * 16) * 136 + rb + mf * 16 + rg] = (bf16)acc[mf][nf][rg];
      __syncthreads();
#pragma unroll
      for (int j = 0; j < 4; ++j) {
        const int flat = j * 4096 + tid * 16;
        const int row = flat >> 8, offb = flat & 255;
        bf16x8_t vv = *(const bf16x8_t*)(st + row * 136 + offb / 2);
        const size_t addr =
            ((size_t)((b * HEADS + h) * DH + row)) * SEQ + s0tok + offb / 2;
        *(bf16x8_t*)(ovT + addr) = vv;
      }
    }
    return;
  }

  const int rbase = m0 + wm * 64 + (lane >> 4) * 4;
  const int cbase = n0 + wn * 32 + lr;
#pragma unroll
  for (int mf = 0; mf < 4; ++mf) {
#pragma unroll
    for (int nf = 0; nf < 2; ++nf) {
      const int c = cbase + nf * 16;
#pragma unroll
      for (int rg = 0; rg < 4; ++rg) {
        const int r = rbase + mf * 16 + rg;
        float v = acc[mf][nf][rg];
        if constexpr (MODE == MODE_RES) {
          const size_t idx = (size_t)r * 512 + c;
          outF[idx] = res[idx] + v;
        } else if constexpr (MODE == MODE_BIAS) {
          const size_t idx = (size_t)r * 512 + c;
          outF[idx] = v + bias[c];
        } else if constexpr (MODE == MODE_SWIGLU2) {
          const size_t idx = (size_t)r * 512 + c;
          const float u1 = v + bias[c];
          const float u2 = acc2[mf][nf][rg] + bias[512 + c];
          const float sig = 1.0f / (1.0f + __expf(-u1));
          outB[idx] = (bf16)(u1 * sig + u2);
        } else {
          const size_t idx = (size_t)r * 512 + c;
          outF[idx] = res[idx] + v + bias[c];
        }
      }
    }
  }
}

// ---------------- causal flash attention: KVBLK=64 + split-K parity -------
// Same schedule as round 5 but register-disciplined (peak ~110 VGPR so the
// 4-waves/EU budget of 128 arch VGPRs holds without AGPR carve-out/spill):
// V loaded in two quads (oa0's before QK, oa1's after P-pack frees s0/s1),
// P-fragment assembly via 8 v_permlane32_swap (replaces 16 shfl + 32 cndmask).
__global__ __launch_bounds__(512, 4) void attn_k(const bf16* __restrict__ Q,
                                                 const bf16* __restrict__ K,
                                                 const bf16* __restrict__ VT,
                                                 bf16* __restrict__ O) {
  const int tid = threadIdx.x;
  const int wave = tid >> 6, lane = tid & 63;
  const int lq = lane & 31, hi = lane >> 5;

  const int wg = blockIdx.x;                 // 0..511
  const int xcd = wg & 7;
  const int bh = xcd * 4 + ((wg >> 3) & 3);
  const int j = wg >> 5;                     // 0..15 block-slot
  const int ts = wave >> 1, parity = wave & 1;
  const int t = (ts == 0) ? j : (ts == 1) ? (63 - j) : (ts == 2) ? (31 - j) : (32 + j);
  const int qw = t * 32;
  const int nkt = t / 2 + 1;                 // 64-wide k-tiles

  const bf16* Qb = Q + (size_t)bh * SEQ * DH;
  const bf16* Kb = K + (size_t)bh * SEQ * DH;
  const bf16* Vb = VT + (size_t)bh * DH * SEQ;

  __shared__ __align__(16) float cls[4][32][72];
  __shared__ float mls[4][32][2];

  bf16x8_t qf[4];
  {
    const bf16* qp = Qb + (size_t)(qw + lq) * DH + 8 * hi;
    qf[0] = *(const bf16x8_t*)(qp);
    qf[1] = *(const bf16x8_t*)(qp + 16);
    qf[2] = *(const bf16x8_t*)(qp + 32);
    qf[3] = *(const bf16x8_t*)(qp + 48);
  }

  f32x16 oa0, oa1;
#pragma unroll
  for (int r = 0; r < 16; ++r) { oa0[r] = 0.f; oa1[r] = 0.f; }
  float mrun = -3.0e38f, lrun = 0.f;

  union U8 { unsigned int u[4]; bf16x8_t v; };

  for (int kt = parity; kt < nkt; kt += 2) {
    // ---- issue oa0's V quad early (latency hides under QK^T) ----
    const bf16* vp0 = Vb + (size_t)lq * SEQ + kt * 64 + 8 * hi;
    bf16x8_t v00 = *(const bf16x8_t*)(vp0);
    bf16x8_t v01 = *(const bf16x8_t*)(vp0 + 16);
    bf16x8_t v02 = *(const bf16x8_t*)(vp0 + 32);
    bf16x8_t v03 = *(const bf16x8_t*)(vp0 + 48);

    // ---- QK^T ----
    const bf16* kp0 = Kb + (size_t)(kt * 64 + lq) * DH + 8 * hi;
    const bf16* kp1 = kp0 + 32 * DH;
    f32x16 s0, s1;
#pragma unroll
    for (int r = 0; r < 16; ++r) { s0[r] = 0.f; s1[r] = 0.f; }
    __builtin_amdgcn_s_setprio(1);
#pragma unroll
    for (int s = 0; s < 4; ++s) {
      s0 = __builtin_amdgcn_mfma_f32_32x32x16_bf16(*(const bf16x8_t*)(kp0 + 16 * s),
                                                   qf[s], s0, 0, 0, 0);
      s1 = __builtin_amdgcn_mfma_f32_32x32x16_bf16(*(const bf16x8_t*)(kp1 + 16 * s),
                                                   qf[s], s1, 0, 0, 0);
    }
    __builtin_amdgcn_s_setprio(0);

    // ---- causal mask (only the final k-tile of this q-tile) ----
    if (kt == nkt - 1) {
      const int qg = qw + lq;
#pragma unroll
      for (int r = 0; r < 16; ++r) {
        const int kl = kt * 64 + (r & 3) + 8 * (r >> 2) + 4 * hi;
        if (kl > qg) s0[r] = -3.0e38f;
        if (kl + 32 > qg) s1[r] = -3.0e38f;
      }
    }

    // ---- online softmax (exp2 domain), defer-rescale (T13) ----
    float mt = -3.0e38f;
#pragma unroll
    for (int r = 0; r < 16; ++r) mt = fmaxf(mt, fmaxf(s0[r], s1[r]));
    mt = fmaxf(mt, __shfl_xor(mt, 32));
    float mbase = mrun;
    if (!__all(mt <= mrun + 8.0f)) {
      mbase = fmaxf(mrun, mt);
      const float alpha = exp2f(mrun - mbase);
      mrun = mbase;
      lrun *= alpha;
#pragma unroll
      for (int r = 0; r < 16; ++r) { oa0[r] *= alpha; oa1[r] *= alpha; }
    }
    float sum = 0.f;
#pragma unroll
    for (int r = 0; r < 16; ++r) {
      const float a = exp2f(s0[r] - mbase); s0[r] = a; sum += a;
      const float bb = exp2f(s1[r] - mbase); s1[r] = bb; sum += bb;
    }
    sum += __shfl_xor(sum, 32);
    lrun += sum;

    // ---- pack P -> PV B-fragments via permlane32_swap (frees s0/s1) ----
    U8 p00, p01, p10, p11;
    {
      unsigned int x0, x1, y0, y1;
      x0 = packbf(s0[0], s0[1]);  x1 = packbf(s0[4], s0[5]);
      y0 = packbf(s0[2], s0[3]);  y1 = packbf(s0[6], s0[7]);
      permswap(x0, x1); permswap(y0, y1);
      p00.u[0] = x0; p00.u[2] = x1; p00.u[1] = y0; p00.u[3] = y1;
      x0 = packbf(s0[8], s0[9]);   x1 = packbf(s0[12], s0[13]);
      y0 = packbf(s0[10], s0[11]); y1 = packbf(s0[14], s0[15]);
      permswap(x0, x1); permswap(y0, y1);
      p01.u[0] = x0; p01.u[2] = x1; p01.u[1] = y0; p01.u[3] = y1;
      x0 = packbf(s1[0], s1[1]);  x1 = packbf(s1[4], s1[5]);
      y0 = packbf(s1[2], s1[3]);  y1 = packbf(s1[6], s1[7]);
      permswap(x0, x1); permswap(y0, y1);
      p10.u[0] = x0; p10.u[2] = x1; p10.u[1] = y0; p10.u[3] = y1;
      x0 = packbf(s1[8], s1[9]);   x1 = packbf(s1[12], s1[13]);
      y0 = packbf(s1[10], s1[11]); y1 = packbf(s1[14], s1[15]);
      permswap(x0, x1); permswap(y0, y1);
      p11.u[0] = x0; p11.u[2] = x1; p11.u[1] = y0; p11.u[3] = y1;
    }

    // ---- oa0 PV (V quad already in regs) ----
    __builtin_amdgcn_s_setprio(1);
    oa0 = __builtin_amdgcn_mfma_f32_32x32x16_bf16(v00, p00.v, oa0, 0, 0, 0);
    oa0 = __builtin_amdgcn_mfma_f32_32x32x16_bf16(v01, p01.v, oa0, 0, 0, 0);
    oa0 = __builtin_amdgcn_mfma_f32_32x32x16_bf16(v02, p10.v, oa0, 0, 0, 0);
    oa0 = __builtin_amdgcn_mfma_f32_32x32x16_bf16(v03, p11.v, oa0, 0, 0, 0);
    __builtin_amdgcn_s_setprio(0);

    // ---- oa1's V quad (issued late; latency partly hidden by oa0 MFMAs) --
    const bf16* vp1 = vp0 + 32 * SEQ;
    bf16x8_t v10 = *(const bf16x8_t*)(vp1);
    bf16x8_t v11 = *(const bf16x8_t*)(vp1 + 16);
    bf16x8_t v12 = *(const bf16x8_t*)(vp1 + 32);
    bf16x8_t v13 = *(const bf16x8_t*)(vp1 + 48);
    __builtin_amdgcn_s_setprio(1);
    oa1 = __builtin_amdgcn_mfma_f32_32x32x16_bf16(v10, p00.v, oa1, 0, 0, 0);
    oa1 = __builtin_amdgcn_mfma_f32_32x32x16_bf16(v11, p01.v, oa1, 0, 0, 0);
    oa1 = __builtin_amdgcn_mfma_f32_32x32x16_bf16(v12, p10.v, oa1, 0, 0, 0);
    oa1 = __builtin_amdgcn_mfma_f32_32x32x16_bf16(v13, p11.v, oa1, 0, 0, 0);
    __builtin_amdgcn_s_setprio(0);
  }

  // ---- combine parity partials ----
  if (parity) {
    float* cp = &cls[ts][lq][0];
#pragma unroll
    for (int t4 = 0; t4 < 4; ++t4) {
      const int d0 = 8 * t4 + 4 * hi;
      f32x4 a = {oa0[4 * t4], oa0[4 * t4 + 1], oa0[4 * t4 + 2], oa0[4 * t4 + 3]};
      f32x4 b = {oa1[4 * t4], oa1[4 * t4 + 1], oa1[4 * t4 + 2], oa1[4 * t4 + 3]};
      *(f32x4*)(cp + d0) = a;
      *(f32x4*)(cp + 32 + d0) = b;
    }
    if (!hi) { mls[ts][lq][0] = mrun; mls[ts][lq][1] = lrun; }
  }
  __syncthreads();
  if (!parity) {
    const float m2 = mls[ts][lq][0], l2 = mls[ts][lq][1];
    const float ms = fmaxf(mrun, m2);
    float b1 = exp2f(mrun - ms), b2 = exp2f(m2 - ms);
    const float linv = 1.0f / (b1 * lrun + b2 * l2);
    b1 *= linv; b2 *= linv;
    const float* cp = &cls[ts][lq][0];
    f32x4 q0[4], q1[4];
#pragma unroll
    for (int t4 = 0; t4 < 4; ++t4) {
      const int d0 = 8 * t4 + 4 * hi;
      q0[t4] = *(const f32x4*)(cp + d0);
      q1[t4] = *(const f32x4*)(cp + 32 + d0);
    }
#pragma unroll
    for (int t4 = 0; t4 < 4; ++t4)
#pragma unroll
      for (int jj = 0; jj < 4; ++jj) {
        oa0[4 * t4 + jj] = b1 * oa0[4 * t4 + jj] + b2 * q0[t4][jj];
        oa1[4 * t4 + jj] = b1 * oa1[4 * t4 + jj] + b2 * q1[t4][jj];
      }
    asm volatile("" ::: "memory");
    bf16* ol = (bf16*)&cls[ts][0][0];  // [32][80]
#pragma unroll
    for (int t4 = 0; t4 < 4; ++t4) {
      const int d0 = 8 * t4 + 4 * hi;
      *(unsigned int*)(ol + lq * 80 + d0)          = packbf(oa0[4 * t4], oa0[4 * t4 + 1]);
      *(unsigned int*)(ol + lq * 80 + d0 + 2)      = packbf(oa0[4 * t4 + 2], oa0[4 * t4 + 3]);
      *(unsigned int*)(ol + lq * 80 + 32 + d0)     = packbf(oa1[4 * t4], oa1[4 * t4 + 1]);
      *(unsigned int*)(ol + lq * 80 + 32 + d0 + 2) = packbf(oa1[4 * t4 + 2], oa1[4 * t4 + 3]);
    }
    const int b = bh >> 3, h = bh & 7;
#pragma unroll
    for (int ps = 0; ps < 4; ++ps) {
      const int flat = ps * 1024 + lane * 16;
      const int qr = flat >> 7, off = flat & 127;
      bf16x8_t vv = *(const bf16x8_t*)((const char*)ol + qr * 160 + off);
      *(bf16x8_t*)(O + ((size_t)(b * SEQ + qw + qr)) * DIM + h * 64 + off / 2) = vv;
    }
  }
}

// ---------------- host launcher ----------------
extern "C" void kernel_launch(void* const* d_in, const int* in_sizes, int n_in,
                              void* d_out, int out_size, void* d_ws, size_t ws_size,
                              hipStream_t stream) {
  const float* x   = (const float*)d_in[0];
  const float* n1g = (const float*)d_in[1];
  const float* n1b = (const float*)d_in[2];
  const float* wq  = (const float*)d_in[3];
  const float* wk  = (const float*)d_in[4];
  const float* wv  = (const float*)d_in[5];
  const float* wo  = (const float*)d_in[6];
  const float* n2g = (const float*)d_in[7];
  const float* n2b = (const float*)d_in[8];
  const float* w1  = (const float*)d_in[9];
  const float* b1  = (const float*)d_in[10];
  const float* ffg = (const float*)d_in[11];
  const float* ffb = (const float*)d_in[12];
  const float* sww = (const float*)d_in[13];
  const float* swb = (const float*)d_in[14];
  const float* w2  = (const float*)d_in[15];
  const float* b2  = (const float*)d_in[16];
  float* out = (float*)d_out;

  char* ws = (char*)d_ws;
  float* x1 = (float*)(ws + 0);            // 16 MiB
  float* x2 = (float*)(ws + 16777216);     // 16 MiB
  bf16* hbuf   = (bf16*)(ws + 33554432);   // 8 MiB
  bf16* qbuf   = (bf16*)(ws + 41943040);   // 8 MiB (q, later g)
  bf16* kbuf   = (bf16*)(ws + 50331648);   // 8 MiB
  bf16* vtbuf  = (bf16*)(ws + 58720256);   // 8 MiB (V^T)
  bf16* obuf   = (bf16*)(ws + 67108864);   // 8 MiB
  bf16* wbase  = (bf16*)(ws + 75497472);   // 4 MiB contiguous bf16 weights
  bf16* wqkv_b = wbase;                    // [1536][512]
  bf16* wo_b   = wbase + 786432;
  bf16* w1_b   = wbase + 1048576;
  bf16* sw_b16 = wbase + 1310720;          // [1024][512]
  bf16* w2_b   = wbase + 1835008;

  cvt_all_k<<<2048, 256, 0, stream>>>(wq, wk, wv, wo, w1, sww, w2, wbase);

  rmsnorm_k<true><<<ROWS / 2, 256, 0, stream>>>(x, n1g, n1b, x1, hbuf);

  gemm_bt_k<MODE_QKV><<<dim3(64, 24), 256, 0, stream>>>(
      hbuf, wqkv_b, nullptr, nullptr, nullptr, nullptr, qbuf, kbuf, vtbuf);

  attn_k<<<512, 512, 0, stream>>>(qbuf, kbuf, vtbuf, obuf);

  gemm_bt_k<MODE_RES><<<dim3(64, 8), 256, 0, stream>>>(
      obuf, wo_b, nullptr, x1, x2, nullptr, nullptr, nullptr, nullptr);

  rmsnorm_k<false><<<ROWS / 2, 256, 0, stream>>>(x2, n2g, n2b, nullptr, hbuf);

  gemm_bt_k<MODE_BIAS><<<dim3(64, 8), 256, 0, stream>>>(
      hbuf, w1_b, b1, nullptr, x1, nullptr, nullptr, nullptr, nullptr);

  rmsnorm_k<false><<<ROWS / 2, 256, 0, stream>>>(x1, ffg, ffb, nullptr, hbuf);

  gemm_bt_k<MODE_SWIGLU2><<<dim3(64, 8), 256, 0, stream>>>(
      hbuf, sw_b16, swb, nullptr, nullptr, qbuf, nullptr, nullptr, nullptr);

  gemm_bt_k<MODE_RESBIAS><<<dim3(64, 8), 256, 0, stream>>>(
      qbuf, w2_b, b2, x2, out, nullptr, nullptr, nullptr, nullptr);
}

// Round 7
// 166.979 us; speedup vs baseline: 2.2812x; 1.1229x over previous
//
#include <hip/hip_runtime.h>
#include <hip/hip_bf16.h>
#include <cstdint>
#include <cstddef>

typedef __bf16 bf16;
typedef __bf16 bf16x4_t __attribute__((ext_vector_type(4)));
typedef __bf16 bf16x8_t __attribute__((ext_vector_type(8)));
typedef float f32x4 __attribute__((ext_vector_type(4)));
typedef float f32x16 __attribute__((ext_vector_type(16)));

#define DEV_INLINE __device__ __forceinline__

constexpr int SEQ = 2048, DIM = 512, HEADS = 8, DH = 64;
constexpr int ROWS = 4 * SEQ;                     // 8192
constexpr float EPSF = 1.1920928955078125e-07f;   // np.finfo(float32).eps
constexpr float RSQRT_DIM = 0.04419417382415922f; // 512^-0.5
constexpr float LOG2E = 1.44269504088896f;

// ---------------- global->LDS direct (16B per lane) ----------------
DEV_INLINE void load_lds16(const void* g, void* l) {
  __builtin_amdgcn_global_load_lds(
      (const __attribute__((address_space(1))) void*)g,
      (__attribute__((address_space(3))) void*)l,
      16, 0, 0);
}

DEV_INLINE unsigned int packbf(float a, float b) {
  union { unsigned int u; bf16 h[2]; } z;
  z.h[0] = (bf16)a;
  z.h[1] = (bf16)b;
  return z.u;
}

// one v_permlane32_swap_b32: exchanges the lane<32/lane>=32 halves of a,b
DEV_INLINE void permswap(unsigned int& a, unsigned int& b) {
  asm volatile("v_permlane32_swap_b32 %0, %1" : "+v"(a), "+v"(b));
}

// ---------------- fused fp32 -> bf16 weight convert (1 launch) ----------
__global__ __launch_bounds__(256) void cvt_all_k(
    const float* __restrict__ wq, const float* __restrict__ wk,
    const float* __restrict__ wv, const float* __restrict__ wo,
    const float* __restrict__ w1, const float* __restrict__ sww,
    const float* __restrict__ w2, bf16* __restrict__ dst) {
  const int i = blockIdx.x * 256 + threadIdx.x;  // 0..524287
  const float* src;
  int local;
  if (i < 196608)      { src = (i < 65536) ? wq : (i < 131072) ? wk : wv; local = i & 65535; }
  else if (i < 262144) { src = wo;  local = i - 196608; }
  else if (i < 327680) { src = w1;  local = i - 262144; }
  else if (i < 458752) { src = sww; local = i - 327680; }
  else                 { src = w2;  local = i - 458752; }
  float4 f = reinterpret_cast<const float4*>(src)[local];
  bf16x4_t o;
  o[0] = (bf16)f.x; o[1] = (bf16)f.y; o[2] = (bf16)f.z; o[3] = (bf16)f.w;
  reinterpret_cast<bf16x4_t*>(dst)[i] = o;
}

// ---------------- RMSNorm (float4 vectorized; 2 rows per block) ----------
template <bool ADDPOS>
__global__ __launch_bounds__(256) void rmsnorm_k(const float* __restrict__ in,
                                                 const float* __restrict__ gain,
                                                 const float* __restrict__ bias,
                                                 float* __restrict__ outF,
                                                 bf16* __restrict__ outB) {
  const int sub = threadIdx.x >> 7;
  const int row = blockIdx.x * 2 + sub;
  const int t = threadIdx.x & 127;
  const float* rp = in + (size_t)row * DIM;
  float4 v = reinterpret_cast<const float4*>(rp)[t];
  if constexpr (ADDPOS) {
    const int s = row & (SEQ - 1);
    const float e0 = (float)(4 * t) * (1.0f / (float)DIM);
    const float e1 = (float)(4 * t + 2) * (1.0f / (float)DIM);
    const float d0 = 1.0f / (powf(10000.0f, e0) + EPSF);
    const float d1 = 1.0f / (powf(10000.0f, e1) + EPSF);
    const float a0 = (float)s * d0, a1 = (float)s * d1;
    v.x += sinf(a0); v.y += cosf(a0);
    v.z += sinf(a1); v.w += cosf(a1);
  }
  float ss = v.x * v.x + v.y * v.y + v.z * v.z + v.w * v.w;
#pragma unroll
  for (int off = 32; off > 0; off >>= 1) ss += __shfl_down(ss, off, 64);
  __shared__ float red[4];
  const int wv = threadIdx.x >> 6;
  if ((threadIdx.x & 63) == 0) red[wv] = ss;
  __syncthreads();
  const float total = red[sub * 2] + red[sub * 2 + 1];
  const float scale = sqrtf(total) * RSQRT_DIM;
  const float inv = 1.0f / (scale + EPSF);
  if constexpr (ADDPOS)
    reinterpret_cast<float4*>(outF + (size_t)row * DIM)[t] = v;
  const float4 g = reinterpret_cast<const float4*>(gain)[t];
  const float4 bb = reinterpret_cast<const float4*>(bias)[t];
  bf16x4_t o;
  o[0] = (bf16)(v.x * inv * g.x + bb.x);
  o[1] = (bf16)(v.y * inv * g.y + bb.y);
  o[2] = (bf16)(v.z * inv * g.z + bb.z);
  o[3] = (bf16)(v.w * inv * g.w + bb.w);
  reinterpret_cast<bf16x4_t*>(outB + (size_t)row * DIM)[t] = o;
}

// ---------------- GEMM: C[M,N] = A[M,512] @ Bt[N,512]^T ----------------
enum { MODE_QKV = 0, MODE_RES = 1, MODE_BIAS = 2, MODE_SWIGLU2 = 3, MODE_RESBIAS = 4 };

template <int MODE>
__global__ __launch_bounds__(256) void gemm_bt_k(
    const bf16* __restrict__ A, const bf16* __restrict__ Bt,
    const float* __restrict__ bias, const float* __restrict__ res,
    float* __restrict__ outF, bf16* __restrict__ outB,
    bf16* __restrict__ oq, bf16* __restrict__ okk, bf16* __restrict__ ovT) {
  constexpr int BELEMS = (MODE == MODE_SWIGLU2) ? 4096 : 2048;
  __shared__ __align__(16) bf16 sA[3][128 * 32];
  __shared__ __align__(16) bf16 sB[3][BELEMS];
  const int tid = threadIdx.x;
  const int wave = tid >> 6, lane = tid & 63;
  const int m0 = blockIdx.x * 128, n0 = blockIdx.y * 64;
  const int wm = wave >> 1, wn = wave & 1;
  const int lr = lane & 15, lk = (lane >> 4) * 8;

  const f32x4 fzero = {0.f, 0.f, 0.f, 0.f};
  f32x4 acc[4][2], acc2[4][2];
#pragma unroll
  for (int i = 0; i < 4; ++i)
#pragma unroll
    for (int j = 0; j < 2; ++j) { acc[i][j] = fzero; acc2[i][j] = fzero; }

  const int off0 = wave * 1024 + lane * 16;
  const int rowS = off0 >> 6, colb = off0 & 63;

  auto stage = [&](int buf, int kt) {
    const int k0 = kt * 32;
    load_lds16((const char*)A + ((size_t)(m0 + rowS) * 512 + k0) * 2 + colb,
               (char*)&sA[buf][0] + off0);
    load_lds16((const char*)A + ((size_t)(m0 + 64 + rowS) * 512 + k0) * 2 + colb,
               (char*)&sA[buf][0] + 4096 + off0);
    load_lds16((const char*)Bt + ((size_t)(n0 + rowS) * 512 + k0) * 2 + colb,
               (char*)&sB[buf][0] + off0);
    if constexpr (MODE == MODE_SWIGLU2)
      load_lds16((const char*)Bt + ((size_t)(512 + n0 + rowS) * 512 + k0) * 2 + colb,
                 (char*)&sB[buf][0] + 4096 + off0);
  };

  stage(0, 0);
  stage(1, 1);
  if constexpr (MODE == MODE_SWIGLU2)
    asm volatile("s_waitcnt vmcnt(4)\ns_barrier" ::: "memory");
  else
    asm volatile("s_waitcnt vmcnt(3)\ns_barrier" ::: "memory");

#pragma unroll
  for (int kt = 0; kt < 16; ++kt) {
    const int cur = kt % 3;
    if (kt + 2 < 16) stage((kt + 2) % 3, kt + 2);
    bf16x8_t af[4], bfr[2], bfr2[2];
#pragma unroll
    for (int mf = 0; mf < 4; ++mf)
      af[mf] = *(const bf16x8_t*)(&sA[cur][0] + (wm * 64 + mf * 16 + lr) * 32 + lk);
#pragma unroll
    for (int nf = 0; nf < 2; ++nf)
      bfr[nf] = *(const bf16x8_t*)(&sB[cur][0] + (wn * 32 + nf * 16 + lr) * 32 + lk);
    if constexpr (MODE == MODE_SWIGLU2) {
#pragma unroll
      for (int nf = 0; nf < 2; ++nf)
        bfr2[nf] = *(const bf16x8_t*)(&sB[cur][0] + 2048 + (wn * 32 + nf * 16 + lr) * 32 + lk);
    }
    asm volatile("s_waitcnt lgkmcnt(0)" ::: "memory");
#pragma unroll
    for (int mf = 0; mf < 4; ++mf)
#pragma unroll
      for (int nf = 0; nf < 2; ++nf) {
        acc[mf][nf] = __builtin_amdgcn_mfma_f32_16x16x32_bf16(af[mf], bfr[nf],
                                                              acc[mf][nf], 0, 0, 0);
        if constexpr (MODE == MODE_SWIGLU2)
          acc2[mf][nf] = __builtin_amdgcn_mfma_f32_16x16x32_bf16(af[mf], bfr2[nf],
                                                                 acc2[mf][nf], 0, 0, 0);
      }
    if (kt < 14) {
      if constexpr (MODE == MODE_SWIGLU2)
        asm volatile("s_waitcnt vmcnt(4)\ns_barrier" ::: "memory");
      else
        asm volatile("s_waitcnt vmcnt(3)\ns_barrier" ::: "memory");
    } else if (kt < 15) {
      asm volatile("s_waitcnt vmcnt(0)\ns_barrier" ::: "memory");
    }
  }

  if constexpr (MODE == MODE_QKV) {
    // ---- LDS-staged vectorized epilogue ----
    const int which = n0 >> 9;          // 0=q 1=k 2=v
    const int h = (n0 >> 6) & 7;
    const int b = m0 >> 11;
    const int s0tok = m0 & 2047;
    bf16* st = &sA[0][0];
    const int rb = wm * 64 + (lane >> 4) * 4;
    const int cb = wn * 32 + lr;
    __syncthreads();
    if (which < 2) {
#pragma unroll
      for (int mf = 0; mf < 4; ++mf)
#pragma unroll
        for (int nf = 0; nf < 2; ++nf)
#pragma unroll
          for (int rg = 0; rg < 4; ++rg) {
            float v = acc[mf][nf][rg];
            if (which == 0) v *= RSQRT_DIM * LOG2E;
            st[(rb + mf * 16 + rg) * 72 + cb + nf * 16] = (bf16)v;
          }
      __syncthreads();
      bf16* dst = which == 0 ? oq : okk;
#pragma unroll
      for (int j = 0; j < 4; ++j) {
        const int flat = j * 4096 + tid * 16;
        const int row = flat >> 7, offb = flat & 127;
        bf16x8_t vv = *(const bf16x8_t*)(st + row * 72 + offb / 2);
        const size_t addr =
            ((size_t)((b * HEADS + h) * SEQ + s0tok + row)) * DH + offb / 2;
        *(bf16x8_t*)(dst + addr) = vv;
      }
    } else {
#pragma unroll
      for (int mf = 0; mf < 4; ++mf)
#pragma unroll
        for (int nf = 0; nf < 2; ++nf)
#pragma unroll
          for (int rg = 0; rg < 4; ++rg)
            st[(cb + nf * 16) * 136 + rb + mf * 16 + rg] = (bf16)acc[mf][nf][rg];
      __syncthreads();
#pragma unroll
      for (int j = 0; j < 4; ++j) {
        const int flat = j * 4096 + tid * 16;
        const int row = flat >> 8, offb = flat & 255;
        bf16x8_t vv = *(const bf16x8_t*)(st + row * 136 + offb / 2);
        const size_t addr =
            ((size_t)((b * HEADS + h) * DH + row)) * SEQ + s0tok + offb / 2;
        *(bf16x8_t*)(ovT + addr) = vv;
      }
    }
    return;
  }

  const int rbase = m0 + wm * 64 + (lane >> 4) * 4;
  const int cbase = n0 + wn * 32 + lr;
#pragma unroll
  for (int mf = 0; mf < 4; ++mf) {
#pragma unroll
    for (int nf = 0; nf < 2; ++nf) {
      const int c = cbase + nf * 16;
#pragma unroll
      for (int rg = 0; rg < 4; ++rg) {
        const int r = rbase + mf * 16 + rg;
        float v = acc[mf][nf][rg];
        if constexpr (MODE == MODE_RES) {
          const size_t idx = (size_t)r * 512 + c;
          outF[idx] = res[idx] + v;
        } else if constexpr (MODE == MODE_BIAS) {
          const size_t idx = (size_t)r * 512 + c;
          outF[idx] = v + bias[c];
        } else if constexpr (MODE == MODE_SWIGLU2) {
          const size_t idx = (size_t)r * 512 + c;
          const float u1 = v + bias[c];
          const float u2 = acc2[mf][nf][rg] + bias[512 + c];
          const float sig = 1.0f / (1.0f + __expf(-u1));
          outB[idx] = (bf16)(u1 * sig + u2);
        } else {
          const size_t idx = (size_t)r * 512 + c;
          outF[idx] = res[idx] + v + bias[c];
        }
      }
    }
  }
}

// ---------------- causal flash attention: LDS-shared K/V tiles ------------
// 512 blocks x 256 thr (4 waves). Block -> (bh, 128 q-rows); wave w owns
// q-rows [qb+32w, qb+32w+32). Per 64-wide k-tile: K (8KB) and V^T (8KB)
// staged ONCE per block into LDS via coalesced global_load_lds with
// XOR-pre-swizzled source (linear LDS dest), double-buffered; all 4 waves
// read fragments via conflict-free swizzled ds_read_b128. Causal: all waves
// run the block's NT iterations (barrier-safe), skipping compute past their
// diagonal; mask only on each wave's last tile. In-register softmax (exp2
// domain, q pre-scaled by log2e/sqrt(D)), defer-rescale, permlane P-pack.
__global__ __launch_bounds__(256, 4) void attn_k(const bf16* __restrict__ Q,
                                                 const bf16* __restrict__ K,
                                                 const bf16* __restrict__ VT,
                                                 bf16* __restrict__ O) {
  const int tid = threadIdx.x;
  const int wave = tid >> 6, lane = tid & 63;
  const int lq = lane & 31, hi = lane >> 5;

  const int wg = blockIdx.x;                 // 0..511
  const int xcd = wg & 7;
  const int bh = xcd * 4 + ((wg >> 3) & 3);
  const int qi = 15 - (wg >> 5);             // long blocks dispatched first
  const int qb = qi * 128;
  const int qw = qb + wave * 32;
  const int NT = qi * 2 + 2;                 // staged k-tiles per block
  const int nkt = qi * 2 + 1 + (wave >> 1);  // tiles this wave computes

  const char* Kg = (const char*)(K + (size_t)bh * SEQ * DH);
  const char* Vg = (const char*)(VT + (size_t)bh * DH * SEQ);
  const bf16* Qp = Q + (size_t)bh * SEQ * DH;

  __shared__ __align__(16) bf16 smem[4][4096];  // [0,1]=K dbuf, [2,3]=V dbuf

  // Q fragments (one-time divergent read, amortized)
  bf16x8_t qf[4];
  {
    const bf16* qp = Qp + (size_t)(qw + lq) * DH + 8 * hi;
    qf[0] = *(const bf16x8_t*)(qp);
    qf[1] = *(const bf16x8_t*)(qp + 16);
    qf[2] = *(const bf16x8_t*)(qp + 32);
    qf[3] = *(const bf16x8_t*)(qp + 48);
  }

  const int slot = lane & 7, rsub = lane >> 3;
  const int sgoff = (slot * 16) ^ (rsub << 4);  // swizzled byte within 128B row

  auto stage = [&](int buf, int kt) {
#pragma unroll
    for (int c = 0; c < 2; ++c) {
      const int row = c * 32 + wave * 8 + rsub;           // 0..63
      const int ldsb = c * 4096 + wave * 1024 + lane * 16;
      load_lds16(Kg + (size_t)(kt * 64 + row) * 128 + sgoff,
                 (char*)&smem[buf][0] + ldsb);
      load_lds16(Vg + (size_t)row * 4096 + (size_t)kt * 128 + sgoff,
                 (char*)&smem[2 + buf][0] + ldsb);
    }
  };

  stage(0, 0);
  asm volatile("s_waitcnt vmcnt(0)" ::: "memory");
  __builtin_amdgcn_s_barrier();

  f32x16 oa0, oa1;
#pragma unroll
  for (int r = 0; r < 16; ++r) { oa0[r] = 0.f; oa1[r] = 0.f; }
  float mrun = -3.0e38f, lrun = 0.f;
  const int xorv = (lq & 7) << 4;

  union U8 { unsigned int u[4]; bf16x8_t v; };

  for (int kt = 0; kt < NT; ++kt) {
    const int buf = kt & 1;
    if (kt + 1 < NT) stage(buf ^ 1, kt + 1);
    if (kt < nkt) {
      const char* kb = (const char*)&smem[buf][0];
      const char* vb = (const char*)&smem[2 + buf][0];

      // ---- QK^T from LDS ----
      f32x16 s0, s1;
#pragma unroll
      for (int r = 0; r < 16; ++r) { s0[r] = 0.f; s1[r] = 0.f; }
      __builtin_amdgcn_s_setprio(1);
#pragma unroll
      for (int s = 0; s < 4; ++s) {
        const int bo = (32 * s + 16 * hi) ^ xorv;
        s0 = __builtin_amdgcn_mfma_f32_32x32x16_bf16(
            *(const bf16x8_t*)(kb + lq * 128 + bo), qf[s], s0, 0, 0, 0);
        s1 = __builtin_amdgcn_mfma_f32_32x32x16_bf16(
            *(const bf16x8_t*)(kb + (32 + lq) * 128 + bo), qf[s], s1, 0, 0, 0);
      }
      __builtin_amdgcn_s_setprio(0);

      // ---- causal mask (only this wave's last tile) ----
      if (kt == nkt - 1) {
        const int qg = qw + lq;
#pragma unroll
        for (int r = 0; r < 16; ++r) {
          const int kl = kt * 64 + (r & 3) + 8 * (r >> 2) + 4 * hi;
          if (kl > qg) s0[r] = -3.0e38f;
          if (kl + 32 > qg) s1[r] = -3.0e38f;
        }
      }

      // ---- online softmax (exp2 domain), defer-rescale ----
      float mt = -3.0e38f;
#pragma unroll
      for (int r = 0; r < 16; ++r) mt = fmaxf(mt, fmaxf(s0[r], s1[r]));
      mt = fmaxf(mt, __shfl_xor(mt, 32));
      float mbase = mrun;
      if (!__all(mt <= mrun + 8.0f)) {
        mbase = fmaxf(mrun, mt);
        const float alpha = exp2f(mrun - mbase);
        mrun = mbase;
        lrun *= alpha;
#pragma unroll
        for (int r = 0; r < 16; ++r) { oa0[r] *= alpha; oa1[r] *= alpha; }
      }
      float sum = 0.f;
#pragma unroll
      for (int r = 0; r < 16; ++r) {
        const float a = exp2f(s0[r] - mbase); s0[r] = a; sum += a;
        const float bb = exp2f(s1[r] - mbase); s1[r] = bb; sum += bb;
      }
      sum += __shfl_xor(sum, 32);
      lrun += sum;

      // ---- pack P -> PV B-fragments via permlane32_swap ----
      U8 p00, p01, p10, p11;
      {
        unsigned int x0, x1, y0, y1;
        x0 = packbf(s0[0], s0[1]);  x1 = packbf(s0[4], s0[5]);
        y0 = packbf(s0[2], s0[3]);  y1 = packbf(s0[6], s0[7]);
        permswap(x0, x1); permswap(y0, y1);
        p00.u[0] = x0; p00.u[2] = x1; p00.u[1] = y0; p00.u[3] = y1;
        x0 = packbf(s0[8], s0[9]);   x1 = packbf(s0[12], s0[13]);
        y0 = packbf(s0[10], s0[11]); y1 = packbf(s0[14], s0[15]);
        permswap(x0, x1); permswap(y0, y1);
        p01.u[0] = x0; p01.u[2] = x1; p01.u[1] = y0; p01.u[3] = y1;
        x0 = packbf(s1[0], s1[1]);  x1 = packbf(s1[4], s1[5]);
        y0 = packbf(s1[2], s1[3]);  y1 = packbf(s1[6], s1[7]);
        permswap(x0, x1); permswap(y0, y1);
        p10.u[0] = x0; p10.u[2] = x1; p10.u[1] = y0; p10.u[3] = y1;
        x0 = packbf(s1[8], s1[9]);   x1 = packbf(s1[12], s1[13]);
        y0 = packbf(s1[10], s1[11]); y1 = packbf(s1[14], s1[15]);
        permswap(x0, x1); permswap(y0, y1);
        p11.u[0] = x0; p11.u[2] = x1; p11.u[1] = y0; p11.u[3] = y1;
      }

      // ---- O^T += V^T . P from LDS ----
      __builtin_amdgcn_s_setprio(1);
      {
        const int b0 = (16 * hi) ^ xorv;
        const int b1 = (32 + 16 * hi) ^ xorv;
        const int b2 = (64 + 16 * hi) ^ xorv;
        const int b3 = (96 + 16 * hi) ^ xorv;
        oa0 = __builtin_amdgcn_mfma_f32_32x32x16_bf16(
            *(const bf16x8_t*)(vb + lq * 128 + b0), p00.v, oa0, 0, 0, 0);
        oa0 = __builtin_amdgcn_mfma_f32_32x32x16_bf16(
            *(const bf16x8_t*)(vb + lq * 128 + b1), p01.v, oa0, 0, 0, 0);
        oa0 = __builtin_amdgcn_mfma_f32_32x32x16_bf16(
            *(const bf16x8_t*)(vb + lq * 128 + b2), p10.v, oa0, 0, 0, 0);
        oa0 = __builtin_amdgcn_mfma_f32_32x32x16_bf16(
            *(const bf16x8_t*)(vb + lq * 128 + b3), p11.v, oa0, 0, 0, 0);
        oa1 = __builtin_amdgcn_mfma_f32_32x32x16_bf16(
            *(const bf16x8_t*)(vb + (32 + lq) * 128 + b0), p00.v, oa1, 0, 0, 0);
        oa1 = __builtin_amdgcn_mfma_f32_32x32x16_bf16(
            *(const bf16x8_t*)(vb + (32 + lq) * 128 + b1), p01.v, oa1, 0, 0, 0);
        oa1 = __builtin_amdgcn_mfma_f32_32x32x16_bf16(
            *(const bf16x8_t*)(vb + (32 + lq) * 128 + b2), p10.v, oa1, 0, 0, 0);
        oa1 = __builtin_amdgcn_mfma_f32_32x32x16_bf16(
            *(const bf16x8_t*)(vb + (32 + lq) * 128 + b3), p11.v, oa1, 0, 0, 0);
      }
      __builtin_amdgcn_s_setprio(0);
    }
    asm volatile("s_waitcnt vmcnt(0)" ::: "memory");
    __builtin_amdgcn_s_barrier();
  }

  // ---- epilogue: /l, transpose via per-wave LDS slice, coalesced store ----
  const float inv = 1.0f / lrun;
  bf16* ol = &smem[0][0] + wave * 2560;  // [32][80] per wave (20KB < 32KB)
#pragma unroll
  for (int t4 = 0; t4 < 4; ++t4) {
    const int d0 = 8 * t4 + 4 * hi;
    *(unsigned int*)(ol + lq * 80 + d0)          = packbf(oa0[4 * t4] * inv, oa0[4 * t4 + 1] * inv);
    *(unsigned int*)(ol + lq * 80 + d0 + 2)      = packbf(oa0[4 * t4 + 2] * inv, oa0[4 * t4 + 3] * inv);
    *(unsigned int*)(ol + lq * 80 + 32 + d0)     = packbf(oa1[4 * t4] * inv, oa1[4 * t4 + 1] * inv);
    *(unsigned int*)(ol + lq * 80 + 32 + d0 + 2) = packbf(oa1[4 * t4 + 2] * inv, oa1[4 * t4 + 3] * inv);
  }
  const int b = bh >> 3, h = bh & 7;
#pragma unroll
  for (int ps = 0; ps < 4; ++ps) {
    const int flat = ps * 1024 + lane * 16;
    const int qr = flat >> 7, off = flat & 127;
    bf16x8_t vv = *(const bf16x8_t*)((const char*)ol + qr * 160 + off);
    *(bf16x8_t*)(O + ((size_t)(b * SEQ + qw + qr)) * DIM + h * 64 + off / 2) = vv;
  }
}

// ---------------- host launcher ----------------
extern "C" void kernel_launch(void* const* d_in, const int* in_sizes, int n_in,
                              void* d_out, int out_size, void* d_ws, size_t ws_size,
                              hipStream_t stream) {
  const float* x   = (const float*)d_in[0];
  const float* n1g = (const float*)d_in[1];
  const float* n1b = (const float*)d_in[2];
  const float* wq  = (const float*)d_in[3];
  const float* wk  = (const float*)d_in[4];
  const float* wv  = (const float*)d_in[5];
  const float* wo  = (const float*)d_in[6];
  const float* n2g = (const float*)d_in[7];
  const float* n2b = (const float*)d_in[8];
  const float* w1  = (const float*)d_in[9];
  const float* b1  = (const float*)d_in[10];
  const float* ffg = (const float*)d_in[11];
  const float* ffb = (const float*)d_in[12];
  const float* sww = (const float*)d_in[13];
  const float* swb = (const float*)d_in[14];
  const float* w2  = (const float*)d_in[15];
  const float* b2  = (const float*)d_in[16];
  float* out = (float*)d_out;

  char* ws = (char*)d_ws;
  float* x1 = (float*)(ws + 0);            // 16 MiB
  float* x2 = (float*)(ws + 16777216);     // 16 MiB
  bf16* hbuf   = (bf16*)(ws + 33554432);   // 8 MiB
  bf16* qbuf   = (bf16*)(ws + 41943040);   // 8 MiB (q, later g)
  bf16* kbuf   = (bf16*)(ws + 50331648);   // 8 MiB
  bf16* vtbuf  = (bf16*)(ws + 58720256);   // 8 MiB (V^T)
  bf16* obuf   = (bf16*)(ws + 67108864);   // 8 MiB
  bf16* wbase  = (bf16*)(ws + 75497472);   // 4 MiB contiguous bf16 weights
  bf16* wqkv_b = wbase;                    // [1536][512]
  bf16* wo_b   = wbase + 786432;
  bf16* w1_b   = wbase + 1048576;
  bf16* sw_b16 = wbase + 1310720;          // [1024][512]
  bf16* w2_b   = wbase + 1835008;

  cvt_all_k<<<2048, 256, 0, stream>>>(wq, wk, wv, wo, w1, sww, w2, wbase);

  rmsnorm_k<true><<<ROWS / 2, 256, 0, stream>>>(x, n1g, n1b, x1, hbuf);

  gemm_bt_k<MODE_QKV><<<dim3(64, 24), 256, 0, stream>>>(
      hbuf, wqkv_b, nullptr, nullptr, nullptr, nullptr, qbuf, kbuf, vtbuf);

  attn_k<<<512, 256, 0, stream>>>(qbuf, kbuf, vtbuf, obuf);

  gemm_bt_k<MODE_RES><<<dim3(64, 8), 256, 0, stream>>>(
      obuf, wo_b, nullptr, x1, x2, nullptr, nullptr, nullptr, nullptr);

  rmsnorm_k<false><<<ROWS / 2, 256, 0, stream>>>(x2, n2g, n2b, nullptr, hbuf);

  gemm_bt_k<MODE_BIAS><<<dim3(64, 8), 256, 0, stream>>>(
      hbuf, w1_b, b1, nullptr, x1, nullptr, nullptr, nullptr, nullptr);

  rmsnorm_k<false><<<ROWS / 2, 256, 0, stream>>>(x1, ffg, ffb, nullptr, hbuf);

  gemm_bt_k<MODE_SWIGLU2><<<dim3(64, 8), 256, 0, stream>>>(
      hbuf, sw_b16, swb, nullptr, nullptr, qbuf, nullptr, nullptr, nullptr);

  gemm_bt_k<MODE_RESBIAS><<<dim3(64, 8), 256, 0, stream>>>(
      qbuf, w2_b, b2, x2, out, nullptr, nullptr, nullptr, nullptr);
}